// Round 1
// baseline (379.082 us; speedup 1.0000x reference)
//
#include <hip/hip_runtime.h>
#include <math.h>

#define NL 512
#define NP 1024
#define HDIM 128

// ---- workspace layout (float offsets) ----
#define WD3M_OFF 0                            // 64 col-means of Wd3 + bd3 mean at [64]
#define M_OFF    128                          // m matrix 512x1024
#define LIG_OFF  (M_OFF + NL*NP)              // lig proj 512x128
#define POC_OFF  (LIG_OFF + NL*HDIM)          // poc proj 1024x128
#define LENH_OFF (POC_OFF + NP*HDIM)          // lig_enh 512x128
#define PENH_OFF (LENH_OFF + NL*HDIM)         // poc_enh 1024x128
#define QKVL_OFF (PENH_OFF + NP*HDIM)         // qkv for lig_enh 512x384
#define QKVP_OFF (QKVL_OFF + NL*384)          // qkv for poc_enh 1024x384
#define PART_OFF (QKVP_OFF + NP*384)          // attn partials: [1536][8 heads][8 slices][18]

__device__ __forceinline__ float dot4f(float4 a, float4 b){
  return fmaf(a.x,b.x, fmaf(a.y,b.y, fmaf(a.z,b.z, a.w*b.w)));
}

// ---------------- prep: wd3m[k] = mean_i Wd3[i][k]; wd3m[64] = mean(bd3) ----------------
__global__ __launch_bounds__(128) void prep_kernel(const float* __restrict__ Wd3,
                                                   const float* __restrict__ bd3,
                                                   float* __restrict__ wsw){
  int t = threadIdx.x;
  if (t < 64){
    float s = 0.f;
    #pragma unroll 8
    for (int i = 0; i < 128; i++) s += Wd3[i*64 + t];
    wsw[t] = s * (1.f/128.f);
  } else if (t == 64){
    float s = 0.f;
    for (int i = 0; i < 128; i++) s += bd3[i];
    wsw[64] = s * (1.f/128.f);
  }
}

// ---------------- proj: lig = LF@Wl.T+bl ; poc = PF@Wp.T+bp (4 rows/block) ----------------
__global__ __launch_bounds__(128) void proj_kernel(const float* __restrict__ lf, const float* __restrict__ pf,
                                                   const float* __restrict__ Wl, const float* __restrict__ bl,
                                                   const float* __restrict__ Wp, const float* __restrict__ bp,
                                                   float* __restrict__ lig, float* __restrict__ poc){
  int t = threadIdx.x;
  int row0 = blockIdx.x * 4;
  const float* in; const float* W; const float* bias; float* out;
  if (row0 < NL){ in = lf + (size_t)row0*HDIM; W = Wl; bias = bl; out = lig + (size_t)row0*HDIM; }
  else { int r = row0 - NL; in = pf + (size_t)r*HDIM; W = Wp; bias = bp; out = poc + (size_t)r*HDIM; }
  __shared__ float sin[4*HDIM];
  for (int idx = t; idx < 4*HDIM; idx += 128) sin[idx] = in[idx];
  __syncthreads();
  float bv = bias[t];
  float a0 = bv, a1 = bv, a2 = bv, a3 = bv;
  const float4* wr = (const float4*)(W + (size_t)t*HDIM);
  const float4* s0 = (const float4*)(sin);
  const float4* s1 = (const float4*)(sin + HDIM);
  const float4* s2 = (const float4*)(sin + 2*HDIM);
  const float4* s3 = (const float4*)(sin + 3*HDIM);
  #pragma unroll 8
  for (int k = 0; k < 32; k++){
    float4 w = wr[k];
    a0 = fmaf(w.x, s0[k].x, fmaf(w.y, s0[k].y, fmaf(w.z, s0[k].z, fmaf(w.w, s0[k].w, a0))));
    a1 = fmaf(w.x, s1[k].x, fmaf(w.y, s1[k].y, fmaf(w.z, s1[k].z, fmaf(w.w, s1[k].w, a1))));
    a2 = fmaf(w.x, s2[k].x, fmaf(w.y, s2[k].y, fmaf(w.z, s2[k].z, fmaf(w.w, s2[k].w, a2))));
    a3 = fmaf(w.x, s3[k].x, fmaf(w.y, s3[k].y, fmaf(w.z, s3[k].z, fmaf(w.w, s3[k].w, a3))));
  }
  out[t] = a0; out[HDIM + t] = a1; out[2*HDIM + t] = a2; out[3*HDIM + t] = a3;
}

// ---------------- m_kernel: m[i][j] = wd3m . relu(Wd2 @ relu(d*Wd1+bd1) + bd2) + bd3m ----------------
__global__ __launch_bounds__(256) void m_kernel(const float* __restrict__ lc, const float* __restrict__ pc,
                                                const float* __restrict__ Wd1, const float* __restrict__ bd1,
                                                const float* __restrict__ Wd2, const float* __restrict__ bd2,
                                                const float* __restrict__ wsw, float* __restrict__ mout){
  __shared__ float sWd1[32], sbd1[32], sWd2[2048], sbd2[64], swd3m[64];
  __shared__ float sbd3m;
  int t = threadIdx.x;
  int i = blockIdx.x;
  int j = blockIdx.y * 256 + t;
  if (t < 32){ sWd1[t] = Wd1[t]; sbd1[t] = bd1[t]; }
  if (t >= 32 && t < 96){ sbd2[t-32] = bd2[t-32]; swd3m[t-32] = wsw[t-32]; }
  if (t == 96) sbd3m = wsw[64];
  for (int idx = t; idx < 2048; idx += 256) sWd2[idx] = Wd2[idx];
  __syncthreads();

  float lx = lc[i*3+0], ly = lc[i*3+1], lz = lc[i*3+2];
  float dx = lx - pc[j*3+0], dy = ly - pc[j*3+1], dz = lz - pc[j*3+2];
  float d = sqrtf(fmaf(dx,dx, fmaf(dy,dy, dz*dz)));

  float4 e1q[8];
  const float4* w1q = (const float4*)sWd1;
  const float4* b1q = (const float4*)sbd1;
  #pragma unroll
  for (int k4 = 0; k4 < 8; k4++){
    float4 w = w1q[k4], b = b1q[k4];
    float4 e;
    e.x = fmaxf(fmaf(d, w.x, b.x), 0.f);
    e.y = fmaxf(fmaf(d, w.y, b.y), 0.f);
    e.z = fmaxf(fmaf(d, w.z, b.z), 0.f);
    e.w = fmaxf(fmaf(d, w.w, b.w), 0.f);
    e1q[k4] = e;
  }
  float mv = sbd3m;
  #pragma unroll 4
  for (int j2 = 0; j2 < 64; j2++){
    const float4* wrow = (const float4*)(sWd2 + j2*32);
    float a0 = 0.f, a1 = 0.f, a2 = 0.f, a3 = 0.f;
    #pragma unroll
    for (int k4 = 0; k4 < 8; k4++){
      float4 w = wrow[k4], e = e1q[k4];
      a0 = fmaf(w.x, e.x, a0);
      a1 = fmaf(w.y, e.y, a1);
      a2 = fmaf(w.z, e.z, a2);
      a3 = fmaf(w.w, e.w, a3);
    }
    float e2v = fmaxf(sbd2[j2] + ((a0+a1)+(a2+a3)), 0.f);
    mv = fmaf(swd3m[j2], e2v, mv);
  }
  mout[(size_t)i*NP + j] = mv;
}

// ---------------- agg+gate ligand: sw_l = softmax(-m row); agg = sw@poc; gate; lig_enh ----------------
__global__ __launch_bounds__(256) void agg_gate_l(const float* __restrict__ msrc, const float* __restrict__ lig,
                                                  const float* __restrict__ poc,
                                                  const float* __restrict__ Wgl, const float* __restrict__ bgl,
                                                  float* __restrict__ lenh){
  int i = blockIdx.x, t = threadIdx.x;
  __shared__ float w[NP];
  __shared__ float red[256];
  __shared__ float sx[HDIM], sa[HDIM];
  const float4* mrow = (const float4*)(msrc + (size_t)i*NP);
  float4 mv = mrow[t];
  float x0 = -mv.x, x1 = -mv.y, x2 = -mv.z, x3 = -mv.w;
  float mx = fmaxf(fmaxf(x0,x1), fmaxf(x2,x3));
  red[t] = mx; __syncthreads();
  #pragma unroll
  for (int s = 128; s > 0; s >>= 1){ if (t < s) red[t] = fmaxf(red[t], red[t+s]); __syncthreads(); }
  mx = red[0]; __syncthreads();
  float e0 = __expf(x0-mx), e1 = __expf(x1-mx), e2 = __expf(x2-mx), e3 = __expf(x3-mx);
  w[t*4+0] = e0; w[t*4+1] = e1; w[t*4+2] = e2; w[t*4+3] = e3;
  red[t] = (e0+e1)+(e2+e3); __syncthreads();
  #pragma unroll
  for (int s = 128; s > 0; s >>= 1){ if (t < s) red[t] += red[t+s]; __syncthreads(); }
  float inv = 1.0f / red[0];
  if (t < HDIM){
    float acc = 0.f;
    #pragma unroll 4
    for (int j = 0; j < NP; j++) acc = fmaf(w[j], poc[(size_t)j*HDIM + t], acc);
    sa[t] = acc * inv;
    sx[t] = lig[(size_t)i*HDIM + t];
  }
  __syncthreads();
  if (t < HDIM){
    float g = bgl[t];
    const float4* wr = (const float4*)(Wgl + (size_t)t*256);
    const float4* xs = (const float4*)sx;
    const float4* as = (const float4*)sa;
    #pragma unroll 8
    for (int k = 0; k < 32; k++) g += dot4f(wr[k], xs[k]);
    #pragma unroll 8
    for (int k = 0; k < 32; k++) g += dot4f(wr[32+k], as[k]);
    g = 1.0f / (1.0f + __expf(-g));
    lenh[(size_t)i*HDIM + t] = fmaf(g, sx[t] - sa[t], sa[t]);  // g*x + (1-g)*a
  }
}

// ---------------- agg+gate pocket: sw_p = softmax(-m col); agg = sw@lig; gate; poc_enh ----------------
__global__ __launch_bounds__(256) void agg_gate_p(const float* __restrict__ msrc, const float* __restrict__ lig,
                                                  const float* __restrict__ poc,
                                                  const float* __restrict__ Wgp, const float* __restrict__ bgp,
                                                  float* __restrict__ penh){
  int j = blockIdx.x, t = threadIdx.x;
  __shared__ float w[NL];
  __shared__ float red[256];
  __shared__ float sx[HDIM], sa[HDIM];
  float x0 = -msrc[(size_t)t*NP + j];
  float x1 = -msrc[(size_t)(t+256)*NP + j];
  float mx = fmaxf(x0, x1);
  red[t] = mx; __syncthreads();
  #pragma unroll
  for (int s = 128; s > 0; s >>= 1){ if (t < s) red[t] = fmaxf(red[t], red[t+s]); __syncthreads(); }
  mx = red[0]; __syncthreads();
  float e0 = __expf(x0-mx), e1 = __expf(x1-mx);
  w[t] = e0; w[t+256] = e1;
  red[t] = e0 + e1; __syncthreads();
  #pragma unroll
  for (int s = 128; s > 0; s >>= 1){ if (t < s) red[t] += red[t+s]; __syncthreads(); }
  float inv = 1.0f / red[0];
  if (t < HDIM){
    float acc = 0.f;
    #pragma unroll 4
    for (int i = 0; i < NL; i++) acc = fmaf(w[i], lig[(size_t)i*HDIM + t], acc);
    sa[t] = acc * inv;
    sx[t] = poc[(size_t)j*HDIM + t];
  }
  __syncthreads();
  if (t < HDIM){
    float g = bgp[t];
    const float4* wr = (const float4*)(Wgp + (size_t)t*256);
    const float4* xs = (const float4*)sx;
    const float4* as = (const float4*)sa;
    #pragma unroll 8
    for (int k = 0; k < 32; k++) g += dot4f(wr[k], xs[k]);
    #pragma unroll 8
    for (int k = 0; k < 32; k++) g += dot4f(wr[32+k], as[k]);
    g = 1.0f / (1.0f + __expf(-g));
    penh[(size_t)j*HDIM + t] = fmaf(g, sx[t] - sa[t], sa[t]);
  }
}

// ---------------- qkv: [lig_enh; poc_enh] @ Wqkv.T + bqkv (4 rows/block, 384 threads) ----------------
__global__ __launch_bounds__(384) void qkv_kernel(const float* __restrict__ lenh, const float* __restrict__ penh,
                                                  const float* __restrict__ Wqkv, const float* __restrict__ bqkv,
                                                  float* __restrict__ qkvl, float* __restrict__ qkvp){
  int t = threadIdx.x;
  int row0 = blockIdx.x * 4;
  const float* in; float* out; int rloc;
  if (row0 < NL){ in = lenh + (size_t)row0*HDIM; out = qkvl; rloc = row0; }
  else { rloc = row0 - NL; in = penh + (size_t)rloc*HDIM; out = qkvp; }
  __shared__ float sin[4*HDIM];
  for (int idx = t; idx < 4*HDIM; idx += 384) sin[idx] = in[idx];
  __syncthreads();
  float bv = bqkv[t];
  float a0 = bv, a1 = bv, a2 = bv, a3 = bv;
  const float4* wr = (const float4*)(Wqkv + (size_t)t*HDIM);
  const float4* s0 = (const float4*)(sin);
  const float4* s1 = (const float4*)(sin + HDIM);
  const float4* s2 = (const float4*)(sin + 2*HDIM);
  const float4* s3 = (const float4*)(sin + 3*HDIM);
  #pragma unroll 8
  for (int k = 0; k < 32; k++){
    float4 w = wr[k];
    a0 = fmaf(w.x, s0[k].x, fmaf(w.y, s0[k].y, fmaf(w.z, s0[k].z, fmaf(w.w, s0[k].w, a0))));
    a1 = fmaf(w.x, s1[k].x, fmaf(w.y, s1[k].y, fmaf(w.z, s1[k].z, fmaf(w.w, s1[k].w, a1))));
    a2 = fmaf(w.x, s2[k].x, fmaf(w.y, s2[k].y, fmaf(w.z, s2[k].z, fmaf(w.w, s2[k].w, a2))));
    a3 = fmaf(w.x, s3[k].x, fmaf(w.y, s3[k].y, fmaf(w.z, s3[k].z, fmaf(w.w, s3[k].w, a3))));
  }
  out[(size_t)(rloc+0)*384 + t] = a0;
  out[(size_t)(rloc+1)*384 + t] = a1;
  out[(size_t)(rloc+2)*384 + t] = a2;
  out[(size_t)(rloc+3)*384 + t] = a3;
}

// ---------------- flash attention with split-K partials ----------------
// block: 128 threads = 16 queries x 8 heads; each block covers 128 keys (one slice).
// partial record: [m, l, O[16]] per (row, head, slice)
__global__ __launch_bounds__(128) void attn_part(const float* __restrict__ qkvl, const float* __restrict__ qkvp,
                                                 float* __restrict__ part){
  int bx = blockIdx.x;
  int t = threadIdx.x;
  const float* qsrc; const float* kvsrc; int qt, slice, rowg0;
  if (bx < 256){ qt = bx >> 3; slice = bx & 7; qsrc = qkvl; kvsrc = qkvp; rowg0 = qt*16; }
  else { int b2 = bx - 256; qt = b2 >> 2; slice = b2 & 3; qsrc = qkvp; kvsrc = qkvl; rowg0 = NL + qt*16; }
  int h = t & 7, q = t >> 3;
  const float4* qp = (const float4*)(qsrc + (size_t)(qt*16+q)*384 + h*16);
  float4 q0 = qp[0], q1 = qp[1], q2 = qp[2], q3 = qp[3];
  float m = -1e30f, l = 0.f;
  float4 O0 = {0,0,0,0}, O1 = {0,0,0,0}, O2 = {0,0,0,0}, O3 = {0,0,0,0};
  __shared__ float sKV[32*256];
  for (int tile = 0; tile < 4; tile++){
    int j0 = slice*128 + tile*32;
    __syncthreads();
    for (int v4 = t; v4 < 2048; v4 += 128){
      int jj = v4 >> 6, c4 = v4 & 63;
      ((float4*)sKV)[v4] = *(const float4*)(kvsrc + (size_t)(j0+jj)*384 + 128 + c4*4);
    }
    __syncthreads();
    #pragma unroll 4
    for (int jj = 0; jj < 32; jj++){
      const float4* kk = (const float4*)(sKV + jj*256 + h*16);
      float s = dot4f(q0, kk[0]) + dot4f(q1, kk[1]) + dot4f(q2, kk[2]) + dot4f(q3, kk[3]);
      s *= 0.25f;
      float mn = fmaxf(m, s);
      float corr = __expf(m - mn);
      float p = __expf(s - mn);
      l = fmaf(l, corr, p);
      const float4* vv = (const float4*)(sKV + jj*256 + 128 + h*16);
      O0.x = fmaf(p, vv[0].x, O0.x*corr); O0.y = fmaf(p, vv[0].y, O0.y*corr);
      O0.z = fmaf(p, vv[0].z, O0.z*corr); O0.w = fmaf(p, vv[0].w, O0.w*corr);
      O1.x = fmaf(p, vv[1].x, O1.x*corr); O1.y = fmaf(p, vv[1].y, O1.y*corr);
      O1.z = fmaf(p, vv[1].z, O1.z*corr); O1.w = fmaf(p, vv[1].w, O1.w*corr);
      O2.x = fmaf(p, vv[2].x, O2.x*corr); O2.y = fmaf(p, vv[2].y, O2.y*corr);
      O2.z = fmaf(p, vv[2].z, O2.z*corr); O2.w = fmaf(p, vv[2].w, O2.w*corr);
      O3.x = fmaf(p, vv[3].x, O3.x*corr); O3.y = fmaf(p, vv[3].y, O3.y*corr);
      O3.z = fmaf(p, vv[3].z, O3.z*corr); O3.w = fmaf(p, vv[3].w, O3.w*corr);
      m = mn;
    }
  }
  float* dst = part + ((size_t)(rowg0+q)*8 + h)*144 + (size_t)slice*18;
  dst[0] = m; dst[1] = l;
  dst[2]  = O0.x; dst[3]  = O0.y; dst[4]  = O0.z; dst[5]  = O0.w;
  dst[6]  = O1.x; dst[7]  = O1.y; dst[8]  = O1.z; dst[9]  = O1.w;
  dst[10] = O2.x; dst[11] = O2.y; dst[12] = O2.z; dst[13] = O2.w;
  dst[14] = O3.x; dst[15] = O3.y; dst[16] = O3.z; dst[17] = O3.w;
}

// ---------------- merge partials + Wo proj + residual + LayerNorm ----------------
__global__ __launch_bounds__(128) void merge_ln(const float* __restrict__ part,
                                                const float* __restrict__ lenh, const float* __restrict__ penh,
                                                const float* __restrict__ Wo, const float* __restrict__ bo,
                                                const float* __restrict__ g_l, const float* __restrict__ be_l,
                                                const float* __restrict__ g_p, const float* __restrict__ be_p,
                                                float* __restrict__ out){
  int r = blockIdx.x, t = threadIdx.x;
  int h = t >> 4, c = t & 15;
  int ns = (r < NL) ? 8 : 4;
  const float* base = part + ((size_t)r*8 + h)*144;
  float M = -1e30f;
  for (int s = 0; s < ns; s++) M = fmaxf(M, base[s*18]);
  float Lsum = 0.f, Osum = 0.f;
  for (int s = 0; s < ns; s++){
    float e = __expf(base[s*18] - M);
    Lsum = fmaf(e, base[s*18+1], Lsum);
    Osum = fmaf(e, base[s*18+2+c], Osum);
  }
  __shared__ float satt[HDIM];
  satt[t] = Osum / Lsum;   // t == h*16+c
  __syncthreads();
  float o = bo[t];
  const float4* wr = (const float4*)(Wo + (size_t)t*HDIM);
  const float4* sv = (const float4*)satt;
  #pragma unroll 8
  for (int k = 0; k < 32; k++) o += dot4f(wr[k], sv[k]);
  const float* enh = (r < NL) ? (lenh + (size_t)r*HDIM) : (penh + (size_t)(r-NL)*HDIM);
  float x = enh[t] + o;
  __shared__ float red[HDIM];
  red[t] = x; __syncthreads();
  #pragma unroll
  for (int s = 64; s > 0; s >>= 1){ if (t < s) red[t] += red[t+s]; __syncthreads(); }
  float mu = red[0] * (1.f/128.f); __syncthreads();
  float dx = x - mu;
  red[t] = dx*dx; __syncthreads();
  #pragma unroll
  for (int s = 64; s > 0; s >>= 1){ if (t < s) red[t] += red[t+s]; __syncthreads(); }
  float var = red[0] * (1.f/128.f);
  float y = dx * rsqrtf(var + 1e-5f);
  if (r < NL){
    y = fmaf(y, g_l[t], be_l[t]);
    out[(size_t)r*HDIM + t] = y;
  } else {
    y = fmaf(y, g_p[t], be_p[t]);
    out[(size_t)NL*HDIM + (size_t)(r-NL)*HDIM + t] = y;
  }
}

extern "C" void kernel_launch(void* const* d_in, const int* in_sizes, int n_in,
                              void* d_out, int out_size, void* d_ws, size_t ws_size,
                              hipStream_t stream){
  const float* lf   = (const float*)d_in[0];
  const float* pf   = (const float*)d_in[1];
  const float* lc   = (const float*)d_in[2];
  const float* pc   = (const float*)d_in[3];
  const float* Wl   = (const float*)d_in[4];
  const float* bl   = (const float*)d_in[5];
  const float* Wp   = (const float*)d_in[6];
  const float* bp   = (const float*)d_in[7];
  const float* Wd1  = (const float*)d_in[8];
  const float* bd1  = (const float*)d_in[9];
  const float* Wd2  = (const float*)d_in[10];
  const float* bd2  = (const float*)d_in[11];
  const float* Wd3  = (const float*)d_in[12];
  const float* bd3  = (const float*)d_in[13];
  const float* Wgl  = (const float*)d_in[14];
  const float* bgl  = (const float*)d_in[15];
  const float* Wgp  = (const float*)d_in[16];
  const float* bgp  = (const float*)d_in[17];
  const float* Wqkv = (const float*)d_in[18];
  const float* bqkv = (const float*)d_in[19];
  const float* Wo   = (const float*)d_in[20];
  const float* bo   = (const float*)d_in[21];
  const float* g_l  = (const float*)d_in[22];
  const float* be_l = (const float*)d_in[23];
  const float* g_p  = (const float*)d_in[24];
  const float* be_p = (const float*)d_in[25];

  float* ws  = (float*)d_ws;
  float* out = (float*)d_out;
  float* wsw  = ws + WD3M_OFF;
  float* mws  = ws + M_OFF;
  float* lig  = ws + LIG_OFF;
  float* poc  = ws + POC_OFF;
  float* lenh = ws + LENH_OFF;
  float* penh = ws + PENH_OFF;
  float* qkvl = ws + QKVL_OFF;
  float* qkvp = ws + QKVP_OFF;
  float* part = ws + PART_OFF;

  prep_kernel<<<1, 128, 0, stream>>>(Wd3, bd3, wsw);
  proj_kernel<<<384, 128, 0, stream>>>(lf, pf, Wl, bl, Wp, bp, lig, poc);
  m_kernel<<<dim3(512, 4), 256, 0, stream>>>(lc, pc, Wd1, bd1, Wd2, bd2, wsw, mws);
  agg_gate_l<<<512, 256, 0, stream>>>(mws, lig, poc, Wgl, bgl, lenh);
  agg_gate_p<<<1024, 256, 0, stream>>>(mws, lig, poc, Wgp, bgp, penh);
  qkv_kernel<<<384, 384, 0, stream>>>(lenh, penh, Wqkv, bqkv, qkvl, qkvp);
  attn_part<<<512, 128, 0, stream>>>(qkvl, qkvp, part);
  merge_ln<<<1536, 128, 0, stream>>>(part, lenh, penh, Wo, bo, g_l, be_l, g_p, be_p, out);
}

// Round 2
// 297.607 us; speedup vs baseline: 1.2738x; 1.2738x over previous
//
#include <hip/hip_runtime.h>
#include <math.h>

#define NL 512
#define NP 1024
#define HDIM 128

// ---- workspace layout (float offsets) ----
#define WD3M_OFF 0                            // 64 col-means of Wd3 + bd3 mean at [64]
#define M_OFF    128                          // m matrix 512x1024
#define LIG_OFF  (M_OFF + NL*NP)              // lig proj 512x128
#define POC_OFF  (LIG_OFF + NL*HDIM)          // poc proj 1024x128
#define LENH_OFF (POC_OFF + NP*HDIM)          // lig_enh 512x128
#define PENH_OFF (LENH_OFF + NL*HDIM)         // poc_enh 1024x128
#define QKVL_OFF (PENH_OFF + NP*HDIM)         // qkv for lig_enh 512x384
#define QKVP_OFF (QKVL_OFF + NL*384)          // qkv for poc_enh 1024x384
#define PART_OFF (QKVP_OFF + NP*384)          // attn partials: [1536][8 heads][8 slices][18]

__device__ __forceinline__ float dot4f(float4 a, float4 b){
  return fmaf(a.x,b.x, fmaf(a.y,b.y, fmaf(a.z,b.z, a.w*b.w)));
}

// ---------------- prep: wd3m[k] = mean_i Wd3[i][k]; wd3m[64] = mean(bd3) ----------------
__global__ __launch_bounds__(128) void prep_kernel(const float* __restrict__ Wd3,
                                                   const float* __restrict__ bd3,
                                                   float* __restrict__ wsw){
  int t = threadIdx.x;
  if (t < 64){
    float s = 0.f;
    #pragma unroll 8
    for (int i = 0; i < 128; i++) s += Wd3[i*64 + t];
    wsw[t] = s * (1.f/128.f);
  } else if (t == 64){
    float s = 0.f;
    for (int i = 0; i < 128; i++) s += bd3[i];
    wsw[64] = s * (1.f/128.f);
  }
}

// ---------------- proj: lig = LF@Wl.T+bl ; poc = PF@Wp.T+bp (4 rows/block) ----------------
__global__ __launch_bounds__(128) void proj_kernel(const float* __restrict__ lf, const float* __restrict__ pf,
                                                   const float* __restrict__ Wl, const float* __restrict__ bl,
                                                   const float* __restrict__ Wp, const float* __restrict__ bp,
                                                   float* __restrict__ lig, float* __restrict__ poc){
  int t = threadIdx.x;
  int row0 = blockIdx.x * 4;
  const float* in; const float* W; const float* bias; float* out;
  if (row0 < NL){ in = lf + (size_t)row0*HDIM; W = Wl; bias = bl; out = lig + (size_t)row0*HDIM; }
  else { int r = row0 - NL; in = pf + (size_t)r*HDIM; W = Wp; bias = bp; out = poc + (size_t)r*HDIM; }
  __shared__ float sin[4*HDIM];
  for (int idx = t; idx < 4*HDIM; idx += 128) sin[idx] = in[idx];
  __syncthreads();
  float bv = bias[t];
  float a0 = bv, a1 = bv, a2 = bv, a3 = bv;
  const float4* wr = (const float4*)(W + (size_t)t*HDIM);
  const float4* s0 = (const float4*)(sin);
  const float4* s1 = (const float4*)(sin + HDIM);
  const float4* s2 = (const float4*)(sin + 2*HDIM);
  const float4* s3 = (const float4*)(sin + 3*HDIM);
  #pragma unroll 8
  for (int k = 0; k < 32; k++){
    float4 w = wr[k];
    a0 = fmaf(w.x, s0[k].x, fmaf(w.y, s0[k].y, fmaf(w.z, s0[k].z, fmaf(w.w, s0[k].w, a0))));
    a1 = fmaf(w.x, s1[k].x, fmaf(w.y, s1[k].y, fmaf(w.z, s1[k].z, fmaf(w.w, s1[k].w, a1))));
    a2 = fmaf(w.x, s2[k].x, fmaf(w.y, s2[k].y, fmaf(w.z, s2[k].z, fmaf(w.w, s2[k].w, a2))));
    a3 = fmaf(w.x, s3[k].x, fmaf(w.y, s3[k].y, fmaf(w.z, s3[k].z, fmaf(w.w, s3[k].w, a3))));
  }
  out[t] = a0; out[HDIM + t] = a1; out[2*HDIM + t] = a2; out[3*HDIM + t] = a3;
}

// ---------------- m_kernel: m[i][j] = wd3m . relu(Wd2 @ relu(d*Wd1+bd1) + bd2) + bd3m ----------------
__global__ __launch_bounds__(256) void m_kernel(const float* __restrict__ lc, const float* __restrict__ pc,
                                                const float* __restrict__ Wd1, const float* __restrict__ bd1,
                                                const float* __restrict__ Wd2, const float* __restrict__ bd2,
                                                const float* __restrict__ wsw, float* __restrict__ mout){
  __shared__ float sWd1[32], sbd1[32], sWd2[2048], sbd2[64], swd3m[64];
  __shared__ float sbd3m;
  int t = threadIdx.x;
  int i = blockIdx.x;
  int j = blockIdx.y * 256 + t;
  if (t < 32){ sWd1[t] = Wd1[t]; sbd1[t] = bd1[t]; }
  if (t >= 32 && t < 96){ sbd2[t-32] = bd2[t-32]; swd3m[t-32] = wsw[t-32]; }
  if (t == 96) sbd3m = wsw[64];
  for (int idx = t; idx < 2048; idx += 256) sWd2[idx] = Wd2[idx];
  __syncthreads();

  float lx = lc[i*3+0], ly = lc[i*3+1], lz = lc[i*3+2];
  float dx = lx - pc[j*3+0], dy = ly - pc[j*3+1], dz = lz - pc[j*3+2];
  float d = sqrtf(fmaf(dx,dx, fmaf(dy,dy, dz*dz)));

  float4 e1q[8];
  const float4* w1q = (const float4*)sWd1;
  const float4* b1q = (const float4*)sbd1;
  #pragma unroll
  for (int k4 = 0; k4 < 8; k4++){
    float4 w = w1q[k4], b = b1q[k4];
    float4 e;
    e.x = fmaxf(fmaf(d, w.x, b.x), 0.f);
    e.y = fmaxf(fmaf(d, w.y, b.y), 0.f);
    e.z = fmaxf(fmaf(d, w.z, b.z), 0.f);
    e.w = fmaxf(fmaf(d, w.w, b.w), 0.f);
    e1q[k4] = e;
  }
  float mv = sbd3m;
  #pragma unroll 4
  for (int j2 = 0; j2 < 64; j2++){
    const float4* wrow = (const float4*)(sWd2 + j2*32);
    float a0 = 0.f, a1 = 0.f, a2 = 0.f, a3 = 0.f;
    #pragma unroll
    for (int k4 = 0; k4 < 8; k4++){
      float4 w = wrow[k4], e = e1q[k4];
      a0 = fmaf(w.x, e.x, a0);
      a1 = fmaf(w.y, e.y, a1);
      a2 = fmaf(w.z, e.z, a2);
      a3 = fmaf(w.w, e.w, a3);
    }
    float e2v = fmaxf(sbd2[j2] + ((a0+a1)+(a2+a3)), 0.f);
    mv = fmaf(swd3m[j2], e2v, mv);
  }
  mout[(size_t)i*NP + j] = mv;
}

// ---------------- fused agg+gate for BOTH directions ----------------
// grid = NL + NP blocks, 1024 threads each.
// Block r < NL: ligand row r — softmax(-m[r,:]) over 1024, agg over poc, gate Wgl -> lenh.
// Block r >= NL: pocket row j=r-NL — softmax(-m[:,j]) over 512, agg over lig, gate Wgp -> penh.
// Split-k: 8 groups of 128 threads each cover 1/8 of the k-range, LDS tree combines.
__global__ __launch_bounds__(1024) void agg_gate_fused(const float* __restrict__ msrc,
                                                       const float* __restrict__ lig, const float* __restrict__ poc,
                                                       const float* __restrict__ Wgl, const float* __restrict__ bgl,
                                                       const float* __restrict__ Wgp, const float* __restrict__ bgp,
                                                       float* __restrict__ lenh, float* __restrict__ penh){
  int r = blockIdx.x, t = threadIdx.x;
  __shared__ float w[NP];
  __shared__ float red[32];
  __shared__ float part[1024];
  __shared__ float sx[HDIM], sa[HDIM];
  bool isLig = (r < NL);
  int n = isLig ? NP : NL;

  float x;
  if (isLig)           x = -msrc[(size_t)r*NP + t];
  else if (t < NL)     x = -msrc[(size_t)t*NP + (r - NL)];
  else                 x = -1e30f;

  // block max (wave shuffle + LDS)
  float v = x;
  #pragma unroll
  for (int off = 32; off; off >>= 1) v = fmaxf(v, __shfl_down(v, off));
  int wid = t >> 6, lane = t & 63;
  if (lane == 0) red[wid] = v;
  __syncthreads();
  if (t == 0){ float mm = red[0]; for (int k = 1; k < 16; k++) mm = fmaxf(mm, red[k]); red[16] = mm; }
  __syncthreads();
  float mx = red[16];

  float e = (t < n) ? __expf(x - mx) : 0.f;
  w[t] = e;
  v = e;
  #pragma unroll
  for (int off = 32; off; off >>= 1) v += __shfl_down(v, off);
  if (lane == 0) red[wid] = v;
  __syncthreads();
  if (t == 0){ float ss = 0.f; for (int k = 0; k < 16; k++) ss += red[k]; red[17] = 1.0f / ss; }
  __syncthreads();
  float inv = red[17];

  // split-k aggregation: 8 groups x 128 cols
  int col = t & 127, g = t >> 7;
  const float* src = isLig ? poc : lig;
  int per = n >> 3;          // 128 (lig) or 64 (poc)
  int j0 = g * per;
  float acc = 0.f;
  #pragma unroll 4
  for (int jj = 0; jj < per; jj++){
    int j = j0 + jj;
    acc = fmaf(w[j], src[(size_t)j*HDIM + col], acc);
  }
  part[t] = acc;
  __syncthreads();
  if (t < 512) part[t] += part[t + 512];
  __syncthreads();
  if (t < 256) part[t] += part[t + 256];
  __syncthreads();
  if (t < 128){
    float a = (part[t] + part[t + 128]) * inv;
    sa[t] = a;
    sx[t] = isLig ? lig[(size_t)r*HDIM + t] : poc[(size_t)(r - NL)*HDIM + t];
  }
  __syncthreads();
  if (t < 128){
    const float* Wg = isLig ? Wgl : Wgp;
    const float* bg = isLig ? bgl : bgp;
    float gacc = bg[t];
    const float4* wr = (const float4*)(Wg + (size_t)t*256);
    const float4* xs = (const float4*)sx;
    const float4* as = (const float4*)sa;
    #pragma unroll 8
    for (int k = 0; k < 32; k++) gacc += dot4f(wr[k], xs[k]);
    #pragma unroll 8
    for (int k = 0; k < 32; k++) gacc += dot4f(wr[32 + k], as[k]);
    gacc = 1.0f / (1.0f + __expf(-gacc));
    float* dst = isLig ? (lenh + (size_t)r*HDIM) : (penh + (size_t)(r - NL)*HDIM);
    dst[t] = fmaf(gacc, sx[t] - sa[t], sa[t]);   // g*x + (1-g)*a
  }
}

// ---------------- qkv: [lig_enh; poc_enh] @ Wqkv.T + bqkv (4 rows/block, 384 threads) ----------------
__global__ __launch_bounds__(384) void qkv_kernel(const float* __restrict__ lenh, const float* __restrict__ penh,
                                                  const float* __restrict__ Wqkv, const float* __restrict__ bqkv,
                                                  float* __restrict__ qkvl, float* __restrict__ qkvp){
  int t = threadIdx.x;
  int row0 = blockIdx.x * 4;
  const float* in; float* out; int rloc;
  if (row0 < NL){ in = lenh + (size_t)row0*HDIM; out = qkvl; rloc = row0; }
  else { rloc = row0 - NL; in = penh + (size_t)rloc*HDIM; out = qkvp; }
  __shared__ float sin[4*HDIM];
  for (int idx = t; idx < 4*HDIM; idx += 384) sin[idx] = in[idx];
  __syncthreads();
  float bv = bqkv[t];
  float a0 = bv, a1 = bv, a2 = bv, a3 = bv;
  const float4* wr = (const float4*)(Wqkv + (size_t)t*HDIM);
  const float4* s0 = (const float4*)(sin);
  const float4* s1 = (const float4*)(sin + HDIM);
  const float4* s2 = (const float4*)(sin + 2*HDIM);
  const float4* s3 = (const float4*)(sin + 3*HDIM);
  #pragma unroll 8
  for (int k = 0; k < 32; k++){
    float4 w = wr[k];
    a0 = fmaf(w.x, s0[k].x, fmaf(w.y, s0[k].y, fmaf(w.z, s0[k].z, fmaf(w.w, s0[k].w, a0))));
    a1 = fmaf(w.x, s1[k].x, fmaf(w.y, s1[k].y, fmaf(w.z, s1[k].z, fmaf(w.w, s1[k].w, a1))));
    a2 = fmaf(w.x, s2[k].x, fmaf(w.y, s2[k].y, fmaf(w.z, s2[k].z, fmaf(w.w, s2[k].w, a2))));
    a3 = fmaf(w.x, s3[k].x, fmaf(w.y, s3[k].y, fmaf(w.z, s3[k].z, fmaf(w.w, s3[k].w, a3))));
  }
  out[(size_t)(rloc+0)*384 + t] = a0;
  out[(size_t)(rloc+1)*384 + t] = a1;
  out[(size_t)(rloc+2)*384 + t] = a2;
  out[(size_t)(rloc+3)*384 + t] = a3;
}

// ---------------- flash attention with split-K partials ----------------
__global__ __launch_bounds__(128) void attn_part(const float* __restrict__ qkvl, const float* __restrict__ qkvp,
                                                 float* __restrict__ part){
  int bx = blockIdx.x;
  int t = threadIdx.x;
  const float* qsrc; const float* kvsrc; int qt, slice, rowg0;
  if (bx < 256){ qt = bx >> 3; slice = bx & 7; qsrc = qkvl; kvsrc = qkvp; rowg0 = qt*16; }
  else { int b2 = bx - 256; qt = b2 >> 2; slice = b2 & 3; qsrc = qkvp; kvsrc = qkvl; rowg0 = NL + qt*16; }
  int h = t & 7, q = t >> 3;
  const float4* qp = (const float4*)(qsrc + (size_t)(qt*16+q)*384 + h*16);
  float4 q0 = qp[0], q1 = qp[1], q2 = qp[2], q3 = qp[3];
  float m = -1e30f, l = 0.f;
  float4 O0 = {0,0,0,0}, O1 = {0,0,0,0}, O2 = {0,0,0,0}, O3 = {0,0,0,0};
  __shared__ float sKV[32*256];
  for (int tile = 0; tile < 4; tile++){
    int j0 = slice*128 + tile*32;
    __syncthreads();
    for (int v4 = t; v4 < 2048; v4 += 128){
      int jj = v4 >> 6, c4 = v4 & 63;
      ((float4*)sKV)[v4] = *(const float4*)(kvsrc + (size_t)(j0+jj)*384 + 128 + c4*4);
    }
    __syncthreads();
    #pragma unroll 4
    for (int jj = 0; jj < 32; jj++){
      const float4* kk = (const float4*)(sKV + jj*256 + h*16);
      float s = dot4f(q0, kk[0]) + dot4f(q1, kk[1]) + dot4f(q2, kk[2]) + dot4f(q3, kk[3]);
      s *= 0.25f;
      float mn = fmaxf(m, s);
      float corr = __expf(m - mn);
      float p = __expf(s - mn);
      l = fmaf(l, corr, p);
      const float4* vv = (const float4*)(sKV + jj*256 + 128 + h*16);
      O0.x = fmaf(p, vv[0].x, O0.x*corr); O0.y = fmaf(p, vv[0].y, O0.y*corr);
      O0.z = fmaf(p, vv[0].z, O0.z*corr); O0.w = fmaf(p, vv[0].w, O0.w*corr);
      O1.x = fmaf(p, vv[1].x, O1.x*corr); O1.y = fmaf(p, vv[1].y, O1.y*corr);
      O1.z = fmaf(p, vv[1].z, O1.z*corr); O1.w = fmaf(p, vv[1].w, O1.w*corr);
      O2.x = fmaf(p, vv[2].x, O2.x*corr); O2.y = fmaf(p, vv[2].y, O2.y*corr);
      O2.z = fmaf(p, vv[2].z, O2.z*corr); O2.w = fmaf(p, vv[2].w, O2.w*corr);
      O3.x = fmaf(p, vv[3].x, O3.x*corr); O3.y = fmaf(p, vv[3].y, O3.y*corr);
      O3.z = fmaf(p, vv[3].z, O3.z*corr); O3.w = fmaf(p, vv[3].w, O3.w*corr);
      m = mn;
    }
  }
  float* dst = part + ((size_t)(rowg0+q)*8 + h)*144 + (size_t)slice*18;
  dst[0] = m; dst[1] = l;
  dst[2]  = O0.x; dst[3]  = O0.y; dst[4]  = O0.z; dst[5]  = O0.w;
  dst[6]  = O1.x; dst[7]  = O1.y; dst[8]  = O1.z; dst[9]  = O1.w;
  dst[10] = O2.x; dst[11] = O2.y; dst[12] = O2.z; dst[13] = O2.w;
  dst[14] = O3.x; dst[15] = O3.y; dst[16] = O3.z; dst[17] = O3.w;
}

// ---------------- merge partials + Wo proj + residual + LayerNorm ----------------
__global__ __launch_bounds__(128) void merge_ln(const float* __restrict__ part,
                                                const float* __restrict__ lenh, const float* __restrict__ penh,
                                                const float* __restrict__ Wo, const float* __restrict__ bo,
                                                const float* __restrict__ g_l, const float* __restrict__ be_l,
                                                const float* __restrict__ g_p, const float* __restrict__ be_p,
                                                float* __restrict__ out){
  int r = blockIdx.x, t = threadIdx.x;
  int h = t >> 4, c = t & 15;
  int ns = (r < NL) ? 8 : 4;
  const float* base = part + ((size_t)r*8 + h)*144;
  float M = -1e30f;
  for (int s = 0; s < ns; s++) M = fmaxf(M, base[s*18]);
  float Lsum = 0.f, Osum = 0.f;
  for (int s = 0; s < ns; s++){
    float e = __expf(base[s*18] - M);
    Lsum = fmaf(e, base[s*18+1], Lsum);
    Osum = fmaf(e, base[s*18+2+c], Osum);
  }
  __shared__ float satt[HDIM];
  satt[t] = Osum / Lsum;   // t == h*16+c
  __syncthreads();
  float o = bo[t];
  const float4* wr = (const float4*)(Wo + (size_t)t*HDIM);
  const float4* sv = (const float4*)satt;
  #pragma unroll 8
  for (int k = 0; k < 32; k++) o += dot4f(wr[k], sv[k]);
  const float* enh = (r < NL) ? (lenh + (size_t)r*HDIM) : (penh + (size_t)(r-NL)*HDIM);
  float x = enh[t] + o;
  __shared__ float red[HDIM];
  red[t] = x; __syncthreads();
  #pragma unroll
  for (int s = 64; s > 0; s >>= 1){ if (t < s) red[t] += red[t+s]; __syncthreads(); }
  float mu = red[0] * (1.f/128.f); __syncthreads();
  float dx = x - mu;
  red[t] = dx*dx; __syncthreads();
  #pragma unroll
  for (int s = 64; s > 0; s >>= 1){ if (t < s) red[t] += red[t+s]; __syncthreads(); }
  float var = red[0] * (1.f/128.f);
  float y = dx * rsqrtf(var + 1e-5f);
  if (r < NL){
    y = fmaf(y, g_l[t], be_l[t]);
    out[(size_t)r*HDIM + t] = y;
  } else {
    y = fmaf(y, g_p[t], be_p[t]);
    out[(size_t)NL*HDIM + (size_t)(r-NL)*HDIM + t] = y;
  }
}

extern "C" void kernel_launch(void* const* d_in, const int* in_sizes, int n_in,
                              void* d_out, int out_size, void* d_ws, size_t ws_size,
                              hipStream_t stream){
  const float* lf   = (const float*)d_in[0];
  const float* pf   = (const float*)d_in[1];
  const float* lc   = (const float*)d_in[2];
  const float* pc   = (const float*)d_in[3];
  const float* Wl   = (const float*)d_in[4];
  const float* bl   = (const float*)d_in[5];
  const float* Wp   = (const float*)d_in[6];
  const float* bp   = (const float*)d_in[7];
  const float* Wd1  = (const float*)d_in[8];
  const float* bd1  = (const float*)d_in[9];
  const float* Wd2  = (const float*)d_in[10];
  const float* bd2  = (const float*)d_in[11];
  const float* Wd3  = (const float*)d_in[12];
  const float* bd3  = (const float*)d_in[13];
  const float* Wgl  = (const float*)d_in[14];
  const float* bgl  = (const float*)d_in[15];
  const float* Wgp  = (const float*)d_in[16];
  const float* bgp  = (const float*)d_in[17];
  const float* Wqkv = (const float*)d_in[18];
  const float* bqkv = (const float*)d_in[19];
  const float* Wo   = (const float*)d_in[20];
  const float* bo   = (const float*)d_in[21];
  const float* g_l  = (const float*)d_in[22];
  const float* be_l = (const float*)d_in[23];
  const float* g_p  = (const float*)d_in[24];
  const float* be_p = (const float*)d_in[25];

  float* ws  = (float*)d_ws;
  float* out = (float*)d_out;
  float* wsw  = ws + WD3M_OFF;
  float* mws  = ws + M_OFF;
  float* lig  = ws + LIG_OFF;
  float* poc  = ws + POC_OFF;
  float* lenh = ws + LENH_OFF;
  float* penh = ws + PENH_OFF;
  float* qkvl = ws + QKVL_OFF;
  float* qkvp = ws + QKVP_OFF;
  float* part = ws + PART_OFF;

  prep_kernel<<<1, 128, 0, stream>>>(Wd3, bd3, wsw);
  proj_kernel<<<384, 128, 0, stream>>>(lf, pf, Wl, bl, Wp, bp, lig, poc);
  m_kernel<<<dim3(512, 4), 256, 0, stream>>>(lc, pc, Wd1, bd1, Wd2, bd2, wsw, mws);
  agg_gate_fused<<<NL + NP, 1024, 0, stream>>>(mws, lig, poc, Wgl, bgl, Wgp, bgp, lenh, penh);
  qkv_kernel<<<384, 384, 0, stream>>>(lenh, penh, Wqkv, bqkv, qkvl, qkvp);
  attn_part<<<512, 128, 0, stream>>>(qkvl, qkvp, part);
  merge_ln<<<1536, 128, 0, stream>>>(part, lenh, penh, Wo, bo, g_l, be_l, g_p, be_p, out);
}

// Round 3
// 263.854 us; speedup vs baseline: 1.4367x; 1.1279x over previous
//
#include <hip/hip_runtime.h>
#include <math.h>

#define NL 512
#define NP 1024
#define HDIM 128

// ---- workspace layout (float offsets) ----
#define WD3M_OFF 0                            // 64 col-means of Wd3 + bd3 mean at [64]
#define M_OFF    128                          // m matrix 512x1024
#define LIG_OFF  (M_OFF + NL*NP)              // lig proj 512x128
#define POC_OFF  (LIG_OFF + NL*HDIM)          // poc proj 1024x128
#define LENH_OFF (POC_OFF + NP*HDIM)          // lig_enh 512x128
#define PENH_OFF (LENH_OFF + NL*HDIM)         // poc_enh 1024x128
#define QKVL_OFF (PENH_OFF + NP*HDIM)         // qkv for lig_enh 512x384
#define QKVP_OFF (QKVL_OFF + NL*384)          // qkv for poc_enh 1024x384
#define PARTL_OFF (QKVP_OFF + NP*384)         // lig partials: [512][8 h][8 slices][18]
#define PARTP_OFF (PARTL_OFF + 512*8*8*18)    // poc partials: [1024][8 h][4 slices][18]

__device__ __forceinline__ float dot4f(float4 a, float4 b){
  return fmaf(a.x,b.x, fmaf(a.y,b.y, fmaf(a.z,b.z, a.w*b.w)));
}

// ---------------- prep: wd3m[k] = mean_i Wd3[i][k]; wd3m[64] = mean(bd3) ----------------
__global__ __launch_bounds__(128) void prep_kernel(const float* __restrict__ Wd3,
                                                   const float* __restrict__ bd3,
                                                   float* __restrict__ wsw){
  int t = threadIdx.x;
  if (t < 64){
    float s = 0.f;
    #pragma unroll 8
    for (int i = 0; i < 128; i++) s += Wd3[i*64 + t];
    wsw[t] = s * (1.f/128.f);
  } else if (t == 64){
    float s = 0.f;
    for (int i = 0; i < 128; i++) s += bd3[i];
    wsw[64] = s * (1.f/128.f);
  }
}

// ---------------- proj: lig = LF@Wl.T+bl ; poc = PF@Wp.T+bp (4 rows/block) ----------------
__global__ __launch_bounds__(128) void proj_kernel(const float* __restrict__ lf, const float* __restrict__ pf,
                                                   const float* __restrict__ Wl, const float* __restrict__ bl,
                                                   const float* __restrict__ Wp, const float* __restrict__ bp,
                                                   float* __restrict__ lig, float* __restrict__ poc){
  int t = threadIdx.x;
  int row0 = blockIdx.x * 4;
  const float* in; const float* W; const float* bias; float* out;
  if (row0 < NL){ in = lf + (size_t)row0*HDIM; W = Wl; bias = bl; out = lig + (size_t)row0*HDIM; }
  else { int r = row0 - NL; in = pf + (size_t)r*HDIM; W = Wp; bias = bp; out = poc + (size_t)r*HDIM; }
  __shared__ float sin[4*HDIM];
  for (int idx = t; idx < 4*HDIM; idx += 128) sin[idx] = in[idx];
  __syncthreads();
  float bv = bias[t];
  float a0 = bv, a1 = bv, a2 = bv, a3 = bv;
  const float4* wr = (const float4*)(W + (size_t)t*HDIM);
  const float4* s0 = (const float4*)(sin);
  const float4* s1 = (const float4*)(sin + HDIM);
  const float4* s2 = (const float4*)(sin + 2*HDIM);
  const float4* s3 = (const float4*)(sin + 3*HDIM);
  #pragma unroll 8
  for (int k = 0; k < 32; k++){
    float4 w = wr[k];
    a0 = fmaf(w.x, s0[k].x, fmaf(w.y, s0[k].y, fmaf(w.z, s0[k].z, fmaf(w.w, s0[k].w, a0))));
    a1 = fmaf(w.x, s1[k].x, fmaf(w.y, s1[k].y, fmaf(w.z, s1[k].z, fmaf(w.w, s1[k].w, a1))));
    a2 = fmaf(w.x, s2[k].x, fmaf(w.y, s2[k].y, fmaf(w.z, s2[k].z, fmaf(w.w, s2[k].w, a2))));
    a3 = fmaf(w.x, s3[k].x, fmaf(w.y, s3[k].y, fmaf(w.z, s3[k].z, fmaf(w.w, s3[k].w, a3))));
  }
  out[t] = a0; out[HDIM + t] = a1; out[2*HDIM + t] = a2; out[3*HDIM + t] = a3;
}

// ---------------- m_kernel: m[i][j] = wd3m . relu(Wd2 @ relu(d*Wd1+bd1) + bd2) + bd3m ----------------
__global__ __launch_bounds__(256) void m_kernel(const float* __restrict__ lc, const float* __restrict__ pc,
                                                const float* __restrict__ Wd1, const float* __restrict__ bd1,
                                                const float* __restrict__ Wd2, const float* __restrict__ bd2,
                                                const float* __restrict__ wsw, float* __restrict__ mout){
  __shared__ float sWd1[32], sbd1[32], sWd2[2048], sbd2[64], swd3m[64];
  __shared__ float sbd3m;
  int t = threadIdx.x;
  int i = blockIdx.x;
  int j = blockIdx.y * 256 + t;
  if (t < 32){ sWd1[t] = Wd1[t]; sbd1[t] = bd1[t]; }
  if (t >= 32 && t < 96){ sbd2[t-32] = bd2[t-32]; swd3m[t-32] = wsw[t-32]; }
  if (t == 96) sbd3m = wsw[64];
  for (int idx = t; idx < 2048; idx += 256) sWd2[idx] = Wd2[idx];
  __syncthreads();

  float lx = lc[i*3+0], ly = lc[i*3+1], lz = lc[i*3+2];
  float dx = lx - pc[j*3+0], dy = ly - pc[j*3+1], dz = lz - pc[j*3+2];
  float d = sqrtf(fmaf(dx,dx, fmaf(dy,dy, dz*dz)));

  float4 e1q[8];
  const float4* w1q = (const float4*)sWd1;
  const float4* b1q = (const float4*)sbd1;
  #pragma unroll
  for (int k4 = 0; k4 < 8; k4++){
    float4 w = w1q[k4], b = b1q[k4];
    float4 e;
    e.x = fmaxf(fmaf(d, w.x, b.x), 0.f);
    e.y = fmaxf(fmaf(d, w.y, b.y), 0.f);
    e.z = fmaxf(fmaf(d, w.z, b.z), 0.f);
    e.w = fmaxf(fmaf(d, w.w, b.w), 0.f);
    e1q[k4] = e;
  }
  float mv = sbd3m;
  #pragma unroll 4
  for (int j2 = 0; j2 < 64; j2++){
    const float4* wrow = (const float4*)(sWd2 + j2*32);
    float a0 = 0.f, a1 = 0.f, a2 = 0.f, a3 = 0.f;
    #pragma unroll
    for (int k4 = 0; k4 < 8; k4++){
      float4 w = wrow[k4], e = e1q[k4];
      a0 = fmaf(w.x, e.x, a0);
      a1 = fmaf(w.y, e.y, a1);
      a2 = fmaf(w.z, e.z, a2);
      a3 = fmaf(w.w, e.w, a3);
    }
    float e2v = fmaxf(sbd2[j2] + ((a0+a1)+(a2+a3)), 0.f);
    mv = fmaf(swd3m[j2], e2v, mv);
  }
  mout[(size_t)i*NP + j] = mv;
}

// ---------------- fused agg+gate for BOTH directions ----------------
__global__ __launch_bounds__(1024) void agg_gate_fused(const float* __restrict__ msrc,
                                                       const float* __restrict__ lig, const float* __restrict__ poc,
                                                       const float* __restrict__ Wgl, const float* __restrict__ bgl,
                                                       const float* __restrict__ Wgp, const float* __restrict__ bgp,
                                                       float* __restrict__ lenh, float* __restrict__ penh){
  int r = blockIdx.x, t = threadIdx.x;
  __shared__ float w[NP];
  __shared__ float red[32];
  __shared__ float part[1024];
  __shared__ float sx[HDIM], sa[HDIM];
  bool isLig = (r < NL);
  int n = isLig ? NP : NL;

  float x;
  if (isLig)           x = -msrc[(size_t)r*NP + t];
  else if (t < NL)     x = -msrc[(size_t)t*NP + (r - NL)];
  else                 x = -1e30f;

  float v = x;
  #pragma unroll
  for (int off = 32; off; off >>= 1) v = fmaxf(v, __shfl_down(v, off));
  int wid = t >> 6, lane = t & 63;
  if (lane == 0) red[wid] = v;
  __syncthreads();
  if (t == 0){ float mm = red[0]; for (int k = 1; k < 16; k++) mm = fmaxf(mm, red[k]); red[16] = mm; }
  __syncthreads();
  float mx = red[16];

  float e = (t < n) ? __expf(x - mx) : 0.f;
  w[t] = e;
  v = e;
  #pragma unroll
  for (int off = 32; off; off >>= 1) v += __shfl_down(v, off);
  if (lane == 0) red[wid] = v;
  __syncthreads();
  if (t == 0){ float ss = 0.f; for (int k = 0; k < 16; k++) ss += red[k]; red[17] = 1.0f / ss; }
  __syncthreads();
  float inv = red[17];

  int col = t & 127, g = t >> 7;
  const float* src = isLig ? poc : lig;
  int per = n >> 3;
  int j0 = g * per;
  float acc = 0.f;
  #pragma unroll 4
  for (int jj = 0; jj < per; jj++){
    int j = j0 + jj;
    acc = fmaf(w[j], src[(size_t)j*HDIM + col], acc);
  }
  part[t] = acc;
  __syncthreads();
  if (t < 512) part[t] += part[t + 512];
  __syncthreads();
  if (t < 256) part[t] += part[t + 256];
  __syncthreads();
  if (t < 128){
    float a = (part[t] + part[t + 128]) * inv;
    sa[t] = a;
    sx[t] = isLig ? lig[(size_t)r*HDIM + t] : poc[(size_t)(r - NL)*HDIM + t];
  }
  __syncthreads();
  if (t < 128){
    const float* Wg = isLig ? Wgl : Wgp;
    const float* bg = isLig ? bgl : bgp;
    float gacc = bg[t];
    const float4* wr = (const float4*)(Wg + (size_t)t*256);
    const float4* xs = (const float4*)sx;
    const float4* as = (const float4*)sa;
    #pragma unroll 8
    for (int k = 0; k < 32; k++) gacc += dot4f(wr[k], xs[k]);
    #pragma unroll 8
    for (int k = 0; k < 32; k++) gacc += dot4f(wr[32 + k], as[k]);
    gacc = 1.0f / (1.0f + __expf(-gacc));
    float* dst = isLig ? (lenh + (size_t)r*HDIM) : (penh + (size_t)(r - NL)*HDIM);
    dst[t] = fmaf(gacc, sx[t] - sa[t], sa[t]);
  }
}

// ---------------- qkv: [lig_enh; poc_enh] @ Wqkv.T + bqkv (4 rows/block, 384 threads) ----------------
__global__ __launch_bounds__(384) void qkv_kernel(const float* __restrict__ lenh, const float* __restrict__ penh,
                                                  const float* __restrict__ Wqkv, const float* __restrict__ bqkv,
                                                  float* __restrict__ qkvl, float* __restrict__ qkvp){
  int t = threadIdx.x;
  int row0 = blockIdx.x * 4;
  const float* in; float* out; int rloc;
  if (row0 < NL){ in = lenh + (size_t)row0*HDIM; out = qkvl; rloc = row0; }
  else { rloc = row0 - NL; in = penh + (size_t)rloc*HDIM; out = qkvp; }
  __shared__ float sin[4*HDIM];
  for (int idx = t; idx < 4*HDIM; idx += 384) sin[idx] = in[idx];
  __syncthreads();
  float bv = bqkv[t];
  float a0 = bv, a1 = bv, a2 = bv, a3 = bv;
  const float4* wr = (const float4*)(Wqkv + (size_t)t*HDIM);
  const float4* s0 = (const float4*)(sin);
  const float4* s1 = (const float4*)(sin + HDIM);
  const float4* s2 = (const float4*)(sin + 2*HDIM);
  const float4* s3 = (const float4*)(sin + 3*HDIM);
  #pragma unroll 8
  for (int k = 0; k < 32; k++){
    float4 w = wr[k];
    a0 = fmaf(w.x, s0[k].x, fmaf(w.y, s0[k].y, fmaf(w.z, s0[k].z, fmaf(w.w, s0[k].w, a0))));
    a1 = fmaf(w.x, s1[k].x, fmaf(w.y, s1[k].y, fmaf(w.z, s1[k].z, fmaf(w.w, s1[k].w, a1))));
    a2 = fmaf(w.x, s2[k].x, fmaf(w.y, s2[k].y, fmaf(w.z, s2[k].z, fmaf(w.w, s2[k].w, a2))));
    a3 = fmaf(w.x, s3[k].x, fmaf(w.y, s3[k].y, fmaf(w.z, s3[k].z, fmaf(w.w, s3[k].w, a3))));
  }
  out[(size_t)(rloc+0)*384 + t] = a0;
  out[(size_t)(rloc+1)*384 + t] = a1;
  out[(size_t)(rloc+2)*384 + t] = a2;
  out[(size_t)(rloc+3)*384 + t] = a3;
}

// ---------------- flash attention, v2 ----------------
// 256 threads = 2 groups x (16 q x 8 h). t = g*128 + h*16 + q  (h-major within group
// -> 16 lanes/h broadcast LDS reads; only 2-way bank aliasing = free).
// Each block covers a 128-key slice; group g handles 64 keys in 4 tiles of 16,
// register-tiled scoring (one rescale per 16 keys). Groups merged in LDS;
// one partial record [m,l,O16] per (row,head,slice) written.
__global__ __launch_bounds__(256) void attn_part(const float* __restrict__ qkvl, const float* __restrict__ qkvp,
                                                 float* __restrict__ partL, float* __restrict__ partP){
  int bx = blockIdx.x;
  int t = threadIdx.x;
  const float* qsrc; const float* kvsrc; int qt, slice; bool isLig;
  if (bx < 256){ isLig = true;  qt = bx >> 3; slice = bx & 7; qsrc = qkvl; kvsrc = qkvp; }
  else { int b2 = bx - 256; isLig = false; qt = b2 >> 2; slice = b2 & 3; qsrc = qkvp; kvsrc = qkvl; }
  int g = t >> 7, tt = t & 127;
  int h = tt >> 4, q = tt & 15;
  int j0 = slice*128 + g*64;

  const float4* qp = (const float4*)(qsrc + (size_t)(qt*16+q)*384 + h*16);
  float4 q0 = qp[0], q1 = qp[1], q2 = qp[2], q3 = qp[3];
  float m = -1e30f, l = 0.f;
  float4 O0 = {0,0,0,0}, O1 = {0,0,0,0}, O2 = {0,0,0,0}, O3 = {0,0,0,0};

  __shared__ float sKV[8192];   // 2 groups x (16 keys x 256 floats) = 32 KB
  float* myKV = sKV + g*4096;

  for (int tile = 0; tile < 4; tile++){
    int jbase = j0 + tile*16;
    __syncthreads();
    #pragma unroll
    for (int n = 0; n < 8; n++){
      int v4 = tt + n*128;
      int jj = v4 >> 6, c4 = v4 & 63;
      ((float4*)myKV)[(size_t)jj*64 + c4] = *(const float4*)(kvsrc + (size_t)(jbase+jj)*384 + 128 + c4*4);
    }
    __syncthreads();
    float s[16];
    #pragma unroll
    for (int jj = 0; jj < 16; jj++){
      const float4* kk = (const float4*)(myKV + jj*256 + h*16);
      s[jj] = (dot4f(q0, kk[0]) + dot4f(q1, kk[1]) + dot4f(q2, kk[2]) + dot4f(q3, kk[3])) * 0.25f;
    }
    float mt = s[0];
    #pragma unroll
    for (int jj = 1; jj < 16; jj++) mt = fmaxf(mt, s[jj]);
    float mn = fmaxf(m, mt);
    float corr = __expf(m - mn);
    l *= corr;
    O0.x*=corr; O0.y*=corr; O0.z*=corr; O0.w*=corr;
    O1.x*=corr; O1.y*=corr; O1.z*=corr; O1.w*=corr;
    O2.x*=corr; O2.y*=corr; O2.z*=corr; O2.w*=corr;
    O3.x*=corr; O3.y*=corr; O3.z*=corr; O3.w*=corr;
    #pragma unroll
    for (int jj = 0; jj < 16; jj++){
      float p = __expf(s[jj] - mn);
      l += p;
      const float4* vv = (const float4*)(myKV + jj*256 + 128 + h*16);
      O0.x = fmaf(p, vv[0].x, O0.x); O0.y = fmaf(p, vv[0].y, O0.y);
      O0.z = fmaf(p, vv[0].z, O0.z); O0.w = fmaf(p, vv[0].w, O0.w);
      O1.x = fmaf(p, vv[1].x, O1.x); O1.y = fmaf(p, vv[1].y, O1.y);
      O1.z = fmaf(p, vv[1].z, O1.z); O1.w = fmaf(p, vv[1].w, O1.w);
      O2.x = fmaf(p, vv[2].x, O2.x); O2.y = fmaf(p, vv[2].y, O2.y);
      O2.z = fmaf(p, vv[2].z, O2.z); O2.w = fmaf(p, vv[2].w, O2.w);
      O3.x = fmaf(p, vv[3].x, O3.x); O3.y = fmaf(p, vv[3].y, O3.y);
      O3.z = fmaf(p, vv[3].z, O3.z); O3.w = fmaf(p, vv[3].w, O3.w);
    }
    m = mn;
  }

  // merge the two groups via LDS (reuse sKV; stride 19 to avoid bank conflicts)
  __syncthreads();
  float* smerge = sKV;
  if (g == 1){
    float* b = smerge + tt*19;
    b[0] = m; b[1] = l;
    b[2]=O0.x; b[3]=O0.y; b[4]=O0.z; b[5]=O0.w;
    b[6]=O1.x; b[7]=O1.y; b[8]=O1.z; b[9]=O1.w;
    b[10]=O2.x; b[11]=O2.y; b[12]=O2.z; b[13]=O2.w;
    b[14]=O3.x; b[15]=O3.y; b[16]=O3.z; b[17]=O3.w;
  }
  __syncthreads();
  if (g == 0){
    const float* b = smerge + tt*19;
    float m1 = b[0], l1 = b[1];
    float M = fmaxf(m, m1);
    float e0 = __expf(m - M), e1 = __expf(m1 - M);
    float L = l*e0 + l1*e1;
    float* dst;
    if (isLig) dst = partL + ((size_t)((qt*16+q)*8 + h)*8 + slice)*18;
    else       dst = partP + ((size_t)((qt*16+q)*8 + h)*4 + slice)*18;
    dst[0] = M; dst[1] = L;
    dst[2]  = O0.x*e0 + b[2]*e1;  dst[3]  = O0.y*e0 + b[3]*e1;
    dst[4]  = O0.z*e0 + b[4]*e1;  dst[5]  = O0.w*e0 + b[5]*e1;
    dst[6]  = O1.x*e0 + b[6]*e1;  dst[7]  = O1.y*e0 + b[7]*e1;
    dst[8]  = O1.z*e0 + b[8]*e1;  dst[9]  = O1.w*e0 + b[9]*e1;
    dst[10] = O2.x*e0 + b[10]*e1; dst[11] = O2.y*e0 + b[11]*e1;
    dst[12] = O2.z*e0 + b[12]*e1; dst[13] = O2.w*e0 + b[13]*e1;
    dst[14] = O3.x*e0 + b[14]*e1; dst[15] = O3.y*e0 + b[15]*e1;
    dst[16] = O3.z*e0 + b[16]*e1; dst[17] = O3.w*e0 + b[17]*e1;
  }
}

// ---------------- merge partials + Wo proj + residual + LayerNorm ----------------
__global__ __launch_bounds__(128) void merge_ln(const float* __restrict__ partL, const float* __restrict__ partP,
                                                const float* __restrict__ lenh, const float* __restrict__ penh,
                                                const float* __restrict__ Wo, const float* __restrict__ bo,
                                                const float* __restrict__ g_l, const float* __restrict__ be_l,
                                                const float* __restrict__ g_p, const float* __restrict__ be_p,
                                                float* __restrict__ out){
  int r = blockIdx.x, t = threadIdx.x;
  int h = t >> 4, c = t & 15;
  int ns; const float* base;
  if (r < NL){ ns = 8; base = partL + ((size_t)(r*8 + h))*8*18; }
  else       { ns = 4; base = partP + ((size_t)((r-NL)*8 + h))*4*18; }
  float M = -1e30f;
  for (int s = 0; s < ns; s++) M = fmaxf(M, base[s*18]);
  float Lsum = 0.f, Osum = 0.f;
  for (int s = 0; s < ns; s++){
    float e = __expf(base[s*18] - M);
    Lsum = fmaf(e, base[s*18+1], Lsum);
    Osum = fmaf(e, base[s*18+2+c], Osum);
  }
  __shared__ float satt[HDIM];
  satt[t] = Osum / Lsum;
  __syncthreads();
  float o = bo[t];
  const float4* wr = (const float4*)(Wo + (size_t)t*HDIM);
  const float4* sv = (const float4*)satt;
  #pragma unroll 8
  for (int k = 0; k < 32; k++) o += dot4f(wr[k], sv[k]);
  const float* enh = (r < NL) ? (lenh + (size_t)r*HDIM) : (penh + (size_t)(r-NL)*HDIM);
  float x = enh[t] + o;
  __shared__ float red[HDIM];
  red[t] = x; __syncthreads();
  #pragma unroll
  for (int s = 64; s > 0; s >>= 1){ if (t < s) red[t] += red[t+s]; __syncthreads(); }
  float mu = red[0] * (1.f/128.f); __syncthreads();
  float dx = x - mu;
  red[t] = dx*dx; __syncthreads();
  #pragma unroll
  for (int s = 64; s > 0; s >>= 1){ if (t < s) red[t] += red[t+s]; __syncthreads(); }
  float var = red[0] * (1.f/128.f);
  float y = dx * rsqrtf(var + 1e-5f);
  if (r < NL){
    y = fmaf(y, g_l[t], be_l[t]);
    out[(size_t)r*HDIM + t] = y;
  } else {
    y = fmaf(y, g_p[t], be_p[t]);
    out[(size_t)NL*HDIM + (size_t)(r-NL)*HDIM + t] = y;
  }
}

extern "C" void kernel_launch(void* const* d_in, const int* in_sizes, int n_in,
                              void* d_out, int out_size, void* d_ws, size_t ws_size,
                              hipStream_t stream){
  const float* lf   = (const float*)d_in[0];
  const float* pf   = (const float*)d_in[1];
  const float* lc   = (const float*)d_in[2];
  const float* pc   = (const float*)d_in[3];
  const float* Wl   = (const float*)d_in[4];
  const float* bl   = (const float*)d_in[5];
  const float* Wp   = (const float*)d_in[6];
  const float* bp   = (const float*)d_in[7];
  const float* Wd1  = (const float*)d_in[8];
  const float* bd1  = (const float*)d_in[9];
  const float* Wd2  = (const float*)d_in[10];
  const float* bd2  = (const float*)d_in[11];
  const float* Wd3  = (const float*)d_in[12];
  const float* bd3  = (const float*)d_in[13];
  const float* Wgl  = (const float*)d_in[14];
  const float* bgl  = (const float*)d_in[15];
  const float* Wgp  = (const float*)d_in[16];
  const float* bgp  = (const float*)d_in[17];
  const float* Wqkv = (const float*)d_in[18];
  const float* bqkv = (const float*)d_in[19];
  const float* Wo   = (const float*)d_in[20];
  const float* bo   = (const float*)d_in[21];
  const float* g_l  = (const float*)d_in[22];
  const float* be_l = (const float*)d_in[23];
  const float* g_p  = (const float*)d_in[24];
  const float* be_p = (const float*)d_in[25];

  float* ws  = (float*)d_ws;
  float* out = (float*)d_out;
  float* wsw   = ws + WD3M_OFF;
  float* mws   = ws + M_OFF;
  float* lig   = ws + LIG_OFF;
  float* poc   = ws + POC_OFF;
  float* lenh  = ws + LENH_OFF;
  float* penh  = ws + PENH_OFF;
  float* qkvl  = ws + QKVL_OFF;
  float* qkvp  = ws + QKVP_OFF;
  float* partL = ws + PARTL_OFF;
  float* partP = ws + PARTP_OFF;

  prep_kernel<<<1, 128, 0, stream>>>(Wd3, bd3, wsw);
  proj_kernel<<<384, 128, 0, stream>>>(lf, pf, Wl, bl, Wp, bp, lig, poc);
  m_kernel<<<dim3(512, 4), 256, 0, stream>>>(lc, pc, Wd1, bd1, Wd2, bd2, wsw, mws);
  agg_gate_fused<<<NL + NP, 1024, 0, stream>>>(mws, lig, poc, Wgl, bgl, Wgp, bgp, lenh, penh);
  qkv_kernel<<<384, 384, 0, stream>>>(lenh, penh, Wqkv, bqkv, qkvl, qkvp);
  attn_part<<<512, 256, 0, stream>>>(qkvl, qkvp, partL, partP);
  merge_ln<<<1536, 128, 0, stream>>>(partL, partP, lenh, penh, Wo, bo, g_l, be_l, g_p, be_p, out);
}

// Round 4
// 237.003 us; speedup vs baseline: 1.5995x; 1.1133x over previous
//
#include <hip/hip_runtime.h>
#include <math.h>

#define NL 512
#define NP 1024
#define HDIM 128

#define TAB_N 8192
#define DMAX 34.65f

// ---- workspace layout (float offsets) ----
#define WD3M_OFF 0                            // 64 col-means of Wd3 + bd3 mean at [64]
#define M_OFF    128                          // m matrix 512x1024
#define LIG_OFF  (M_OFF + NL*NP)              // lig proj 512x128
#define POC_OFF  (LIG_OFF + NL*HDIM)          // poc proj 1024x128
#define LENH_OFF (POC_OFF + NP*HDIM)          // lig_enh 512x128
#define PENH_OFF (LENH_OFF + NL*HDIM)         // poc_enh 1024x128
#define QKVL_OFF (PENH_OFF + NP*HDIM)         // qkv for lig_enh 512x384  (also reused as m(d) table before qkv runs)
#define QKVP_OFF (QKVL_OFF + NL*384)          // qkv for poc_enh 1024x384
#define PARTL_OFF (QKVP_OFF + NP*384)         // lig partials: [512][8 h][8 slices][18]
#define PARTP_OFF (PARTL_OFF + 512*8*8*18)    // poc partials: [1024][8 h][4 slices][18]
#define TAB_OFF  QKVL_OFF                     // table is consumed by m_lut before qkv_kernel writes here

__device__ __forceinline__ float dot4f(float4 a, float4 b){
  return fmaf(a.x,b.x, fmaf(a.y,b.y, fmaf(a.z,b.z, a.w*b.w)));
}

// ---------------- prep: wd3m[k] = mean_i Wd3[i][k]; wd3m[64] = mean(bd3) ----------------
__global__ __launch_bounds__(128) void prep_kernel(const float* __restrict__ Wd3,
                                                   const float* __restrict__ bd3,
                                                   float* __restrict__ wsw){
  int t = threadIdx.x;
  if (t < 64){
    float s = 0.f;
    #pragma unroll 8
    for (int i = 0; i < 128; i++) s += Wd3[i*64 + t];
    wsw[t] = s * (1.f/128.f);
  } else if (t == 64){
    float s = 0.f;
    for (int i = 0; i < 128; i++) s += bd3[i];
    wsw[64] = s * (1.f/128.f);
  }
}

// ---------------- proj: lig = LF@Wl.T+bl ; poc = PF@Wp.T+bp (4 rows/block) ----------------
__global__ __launch_bounds__(128) void proj_kernel(const float* __restrict__ lf, const float* __restrict__ pf,
                                                   const float* __restrict__ Wl, const float* __restrict__ bl,
                                                   const float* __restrict__ Wp, const float* __restrict__ bp,
                                                   float* __restrict__ lig, float* __restrict__ poc){
  int t = threadIdx.x;
  int row0 = blockIdx.x * 4;
  const float* in; const float* W; const float* bias; float* out;
  if (row0 < NL){ in = lf + (size_t)row0*HDIM; W = Wl; bias = bl; out = lig + (size_t)row0*HDIM; }
  else { int r = row0 - NL; in = pf + (size_t)r*HDIM; W = Wp; bias = bp; out = poc + (size_t)r*HDIM; }
  __shared__ float sin[4*HDIM];
  for (int idx = t; idx < 4*HDIM; idx += 128) sin[idx] = in[idx];
  __syncthreads();
  float bv = bias[t];
  float a0 = bv, a1 = bv, a2 = bv, a3 = bv;
  const float4* wr = (const float4*)(W + (size_t)t*HDIM);
  const float4* s0 = (const float4*)(sin);
  const float4* s1 = (const float4*)(sin + HDIM);
  const float4* s2 = (const float4*)(sin + 2*HDIM);
  const float4* s3 = (const float4*)(sin + 3*HDIM);
  #pragma unroll 8
  for (int k = 0; k < 32; k++){
    float4 w = wr[k];
    a0 = fmaf(w.x, s0[k].x, fmaf(w.y, s0[k].y, fmaf(w.z, s0[k].z, fmaf(w.w, s0[k].w, a0))));
    a1 = fmaf(w.x, s1[k].x, fmaf(w.y, s1[k].y, fmaf(w.z, s1[k].z, fmaf(w.w, s1[k].w, a1))));
    a2 = fmaf(w.x, s2[k].x, fmaf(w.y, s2[k].y, fmaf(w.z, s2[k].z, fmaf(w.w, s2[k].w, a2))));
    a3 = fmaf(w.x, s3[k].x, fmaf(w.y, s3[k].y, fmaf(w.z, s3[k].z, fmaf(w.w, s3[k].w, a3))));
  }
  out[t] = a0; out[HDIM + t] = a1; out[2*HDIM + t] = a2; out[3*HDIM + t] = a3;
}

// ---------------- table: tab[idx] = m(idx * DMAX/(TAB_N-1)) via full MLP ----------------
// m(d) = wd3m . relu(Wd2 @ relu(d*Wd1+bd1) + bd2) + bd3m  — piecewise-linear in d.
__global__ __launch_bounds__(256) void table_kernel(const float* __restrict__ Wd1, const float* __restrict__ bd1,
                                                    const float* __restrict__ Wd2, const float* __restrict__ bd2,
                                                    const float* __restrict__ wsw, float* __restrict__ tab){
  __shared__ float sWd1[32], sbd1[32], sWd2[2048], sbd2[64], swd3m[64];
  __shared__ float sbd3m;
  int t = threadIdx.x;
  int idx = blockIdx.x * 256 + t;
  if (t < 32){ sWd1[t] = Wd1[t]; sbd1[t] = bd1[t]; }
  if (t >= 32 && t < 96){ sbd2[t-32] = bd2[t-32]; swd3m[t-32] = wsw[t-32]; }
  if (t == 96) sbd3m = wsw[64];
  for (int k = t; k < 2048; k += 256) sWd2[k] = Wd2[k];
  __syncthreads();

  float d = (float)idx * (DMAX / (float)(TAB_N - 1));

  float4 e1q[8];
  const float4* w1q = (const float4*)sWd1;
  const float4* b1q = (const float4*)sbd1;
  #pragma unroll
  for (int k4 = 0; k4 < 8; k4++){
    float4 w = w1q[k4], b = b1q[k4];
    float4 e;
    e.x = fmaxf(fmaf(d, w.x, b.x), 0.f);
    e.y = fmaxf(fmaf(d, w.y, b.y), 0.f);
    e.z = fmaxf(fmaf(d, w.z, b.z), 0.f);
    e.w = fmaxf(fmaf(d, w.w, b.w), 0.f);
    e1q[k4] = e;
  }
  float mv = sbd3m;
  #pragma unroll 4
  for (int j2 = 0; j2 < 64; j2++){
    const float4* wrow = (const float4*)(sWd2 + j2*32);
    float a0 = 0.f, a1 = 0.f, a2 = 0.f, a3 = 0.f;
    #pragma unroll
    for (int k4 = 0; k4 < 8; k4++){
      float4 w = wrow[k4], e = e1q[k4];
      a0 = fmaf(w.x, e.x, a0);
      a1 = fmaf(w.y, e.y, a1);
      a2 = fmaf(w.z, e.z, a2);
      a3 = fmaf(w.w, e.w, a3);
    }
    float e2v = fmaxf(sbd2[j2] + ((a0+a1)+(a2+a3)), 0.f);
    mv = fmaf(swd3m[j2], e2v, mv);
  }
  tab[idx] = mv;
}

// ---------------- m via table lookup: one block per ligand i, 4 j per thread ----------------
__global__ __launch_bounds__(256) void m_lut_kernel(const float* __restrict__ lc, const float* __restrict__ pc,
                                                    const float* __restrict__ tab, float* __restrict__ mout){
  __shared__ float stab[TAB_N];
  int t = threadIdx.x, i = blockIdx.x;
  for (int k = t; k < TAB_N/4; k += 256) ((float4*)stab)[k] = ((const float4*)tab)[k];
  __syncthreads();
  float lx = lc[i*3+0], ly = lc[i*3+1], lz = lc[i*3+2];
  const float4* pc4 = (const float4*)pc;
  float4 A = pc4[3*t], B = pc4[3*t+1], C = pc4[3*t+2];
  const float inv_h = (float)(TAB_N - 1) / DMAX;
  float dxs[4], dys[4], dzs[4];
  dxs[0]=lx-A.x; dys[0]=ly-A.y; dzs[0]=lz-A.z;
  dxs[1]=lx-A.w; dys[1]=ly-B.x; dzs[1]=lz-B.y;
  dxs[2]=lx-B.z; dys[2]=ly-B.w; dzs[2]=lz-C.x;
  dxs[3]=lx-C.y; dys[3]=ly-C.z; dzs[3]=lz-C.w;
  float r[4];
  #pragma unroll
  for (int k = 0; k < 4; k++){
    float d = sqrtf(fmaf(dxs[k],dxs[k], fmaf(dys[k],dys[k], dzs[k]*dzs[k])));
    float x = d * inv_h;
    int i0 = (int)x;
    i0 = (i0 > TAB_N-2) ? (TAB_N-2) : i0;
    float f = x - (float)i0;
    float v0 = stab[i0], v1 = stab[i0+1];
    r[k] = fmaf(f, v1 - v0, v0);
  }
  float4 rv = {r[0], r[1], r[2], r[3]};
  ((float4*)(mout + (size_t)i*NP))[t] = rv;
}

// ---------------- fused agg+gate for BOTH directions ----------------
__global__ __launch_bounds__(1024) void agg_gate_fused(const float* __restrict__ msrc,
                                                       const float* __restrict__ lig, const float* __restrict__ poc,
                                                       const float* __restrict__ Wgl, const float* __restrict__ bgl,
                                                       const float* __restrict__ Wgp, const float* __restrict__ bgp,
                                                       float* __restrict__ lenh, float* __restrict__ penh){
  int r = blockIdx.x, t = threadIdx.x;
  __shared__ float w[NP];
  __shared__ float red[32];
  __shared__ float part[1024];
  __shared__ float sx[HDIM], sa[HDIM];
  bool isLig = (r < NL);
  int n = isLig ? NP : NL;

  float x;
  if (isLig)           x = -msrc[(size_t)r*NP + t];
  else if (t < NL)     x = -msrc[(size_t)t*NP + (r - NL)];
  else                 x = -1e30f;

  float v = x;
  #pragma unroll
  for (int off = 32; off; off >>= 1) v = fmaxf(v, __shfl_down(v, off));
  int wid = t >> 6, lane = t & 63;
  if (lane == 0) red[wid] = v;
  __syncthreads();
  if (t == 0){ float mm = red[0]; for (int k = 1; k < 16; k++) mm = fmaxf(mm, red[k]); red[16] = mm; }
  __syncthreads();
  float mx = red[16];

  float e = (t < n) ? __expf(x - mx) : 0.f;
  w[t] = e;
  v = e;
  #pragma unroll
  for (int off = 32; off; off >>= 1) v += __shfl_down(v, off);
  if (lane == 0) red[wid] = v;
  __syncthreads();
  if (t == 0){ float ss = 0.f; for (int k = 0; k < 16; k++) ss += red[k]; red[17] = 1.0f / ss; }
  __syncthreads();
  float inv = red[17];

  int col = t & 127, g = t >> 7;
  const float* src = isLig ? poc : lig;
  int per = n >> 3;
  int j0 = g * per;
  float acc = 0.f;
  #pragma unroll 4
  for (int jj = 0; jj < per; jj++){
    int j = j0 + jj;
    acc = fmaf(w[j], src[(size_t)j*HDIM + col], acc);
  }
  part[t] = acc;
  __syncthreads();
  if (t < 512) part[t] += part[t + 512];
  __syncthreads();
  if (t < 256) part[t] += part[t + 256];
  __syncthreads();
  if (t < 128){
    float a = (part[t] + part[t + 128]) * inv;
    sa[t] = a;
    sx[t] = isLig ? lig[(size_t)r*HDIM + t] : poc[(size_t)(r - NL)*HDIM + t];
  }
  __syncthreads();
  if (t < 128){
    const float* Wg = isLig ? Wgl : Wgp;
    const float* bg = isLig ? bgl : bgp;
    float gacc = bg[t];
    const float4* wr = (const float4*)(Wg + (size_t)t*256);
    const float4* xs = (const float4*)sx;
    const float4* as = (const float4*)sa;
    #pragma unroll 8
    for (int k = 0; k < 32; k++) gacc += dot4f(wr[k], xs[k]);
    #pragma unroll 8
    for (int k = 0; k < 32; k++) gacc += dot4f(wr[32 + k], as[k]);
    gacc = 1.0f / (1.0f + __expf(-gacc));
    float* dst = isLig ? (lenh + (size_t)r*HDIM) : (penh + (size_t)(r - NL)*HDIM);
    dst[t] = fmaf(gacc, sx[t] - sa[t], sa[t]);
  }
}

// ---------------- qkv: [lig_enh; poc_enh] @ Wqkv.T + bqkv (4 rows/block, 384 threads) ----------------
__global__ __launch_bounds__(384) void qkv_kernel(const float* __restrict__ lenh, const float* __restrict__ penh,
                                                  const float* __restrict__ Wqkv, const float* __restrict__ bqkv,
                                                  float* __restrict__ qkvl, float* __restrict__ qkvp){
  int t = threadIdx.x;
  int row0 = blockIdx.x * 4;
  const float* in; float* out; int rloc;
  if (row0 < NL){ in = lenh + (size_t)row0*HDIM; out = qkvl; rloc = row0; }
  else { rloc = row0 - NL; in = penh + (size_t)rloc*HDIM; out = qkvp; }
  __shared__ float sin[4*HDIM];
  for (int idx = t; idx < 4*HDIM; idx += 384) sin[idx] = in[idx];
  __syncthreads();
  float bv = bqkv[t];
  float a0 = bv, a1 = bv, a2 = bv, a3 = bv;
  const float4* wr = (const float4*)(Wqkv + (size_t)t*HDIM);
  const float4* s0 = (const float4*)(sin);
  const float4* s1 = (const float4*)(sin + HDIM);
  const float4* s2 = (const float4*)(sin + 2*HDIM);
  const float4* s3 = (const float4*)(sin + 3*HDIM);
  #pragma unroll 8
  for (int k = 0; k < 32; k++){
    float4 w = wr[k];
    a0 = fmaf(w.x, s0[k].x, fmaf(w.y, s0[k].y, fmaf(w.z, s0[k].z, fmaf(w.w, s0[k].w, a0))));
    a1 = fmaf(w.x, s1[k].x, fmaf(w.y, s1[k].y, fmaf(w.z, s1[k].z, fmaf(w.w, s1[k].w, a1))));
    a2 = fmaf(w.x, s2[k].x, fmaf(w.y, s2[k].y, fmaf(w.z, s2[k].z, fmaf(w.w, s2[k].w, a2))));
    a3 = fmaf(w.x, s3[k].x, fmaf(w.y, s3[k].y, fmaf(w.z, s3[k].z, fmaf(w.w, s3[k].w, a3))));
  }
  out[(size_t)(rloc+0)*384 + t] = a0;
  out[(size_t)(rloc+1)*384 + t] = a1;
  out[(size_t)(rloc+2)*384 + t] = a2;
  out[(size_t)(rloc+3)*384 + t] = a3;
}

// ---------------- flash attention, v2 (h-major lanes; 2 split-k groups per block) ----------------
__global__ __launch_bounds__(256) void attn_part(const float* __restrict__ qkvl, const float* __restrict__ qkvp,
                                                 float* __restrict__ partL, float* __restrict__ partP){
  int bx = blockIdx.x;
  int t = threadIdx.x;
  const float* qsrc; const float* kvsrc; int qt, slice; bool isLig;
  if (bx < 256){ isLig = true;  qt = bx >> 3; slice = bx & 7; qsrc = qkvl; kvsrc = qkvp; }
  else { int b2 = bx - 256; isLig = false; qt = b2 >> 2; slice = b2 & 3; qsrc = qkvp; kvsrc = qkvl; }
  int g = t >> 7, tt = t & 127;
  int h = tt >> 4, q = tt & 15;
  int j0 = slice*128 + g*64;

  const float4* qp = (const float4*)(qsrc + (size_t)(qt*16+q)*384 + h*16);
  float4 q0 = qp[0], q1 = qp[1], q2 = qp[2], q3 = qp[3];
  float m = -1e30f, l = 0.f;
  float4 O0 = {0,0,0,0}, O1 = {0,0,0,0}, O2 = {0,0,0,0}, O3 = {0,0,0,0};

  __shared__ float sKV[8192];
  float* myKV = sKV + g*4096;

  for (int tile = 0; tile < 4; tile++){
    int jbase = j0 + tile*16;
    __syncthreads();
    #pragma unroll
    for (int n = 0; n < 8; n++){
      int v4 = tt + n*128;
      int jj = v4 >> 6, c4 = v4 & 63;
      ((float4*)myKV)[(size_t)jj*64 + c4] = *(const float4*)(kvsrc + (size_t)(jbase+jj)*384 + 128 + c4*4);
    }
    __syncthreads();
    float s[16];
    #pragma unroll
    for (int jj = 0; jj < 16; jj++){
      const float4* kk = (const float4*)(myKV + jj*256 + h*16);
      s[jj] = (dot4f(q0, kk[0]) + dot4f(q1, kk[1]) + dot4f(q2, kk[2]) + dot4f(q3, kk[3])) * 0.25f;
    }
    float mt = s[0];
    #pragma unroll
    for (int jj = 1; jj < 16; jj++) mt = fmaxf(mt, s[jj]);
    float mn = fmaxf(m, mt);
    float corr = __expf(m - mn);
    l *= corr;
    O0.x*=corr; O0.y*=corr; O0.z*=corr; O0.w*=corr;
    O1.x*=corr; O1.y*=corr; O1.z*=corr; O1.w*=corr;
    O2.x*=corr; O2.y*=corr; O2.z*=corr; O2.w*=corr;
    O3.x*=corr; O3.y*=corr; O3.z*=corr; O3.w*=corr;
    #pragma unroll
    for (int jj = 0; jj < 16; jj++){
      float p = __expf(s[jj] - mn);
      l += p;
      const float4* vv = (const float4*)(myKV + jj*256 + 128 + h*16);
      O0.x = fmaf(p, vv[0].x, O0.x); O0.y = fmaf(p, vv[0].y, O0.y);
      O0.z = fmaf(p, vv[0].z, O0.z); O0.w = fmaf(p, vv[0].w, O0.w);
      O1.x = fmaf(p, vv[1].x, O1.x); O1.y = fmaf(p, vv[1].y, O1.y);
      O1.z = fmaf(p, vv[1].z, O1.z); O1.w = fmaf(p, vv[1].w, O1.w);
      O2.x = fmaf(p, vv[2].x, O2.x); O2.y = fmaf(p, vv[2].y, O2.y);
      O2.z = fmaf(p, vv[2].z, O2.z); O2.w = fmaf(p, vv[2].w, O2.w);
      O3.x = fmaf(p, vv[3].x, O3.x); O3.y = fmaf(p, vv[3].y, O3.y);
      O3.z = fmaf(p, vv[3].z, O3.z); O3.w = fmaf(p, vv[3].w, O3.w);
    }
    m = mn;
  }

  __syncthreads();
  float* smerge = sKV;
  if (g == 1){
    float* b = smerge + tt*19;
    b[0] = m; b[1] = l;
    b[2]=O0.x; b[3]=O0.y; b[4]=O0.z; b[5]=O0.w;
    b[6]=O1.x; b[7]=O1.y; b[8]=O1.z; b[9]=O1.w;
    b[10]=O2.x; b[11]=O2.y; b[12]=O2.z; b[13]=O2.w;
    b[14]=O3.x; b[15]=O3.y; b[16]=O3.z; b[17]=O3.w;
  }
  __syncthreads();
  if (g == 0){
    const float* b = smerge + tt*19;
    float m1 = b[0], l1 = b[1];
    float M = fmaxf(m, m1);
    float e0 = __expf(m - M), e1 = __expf(m1 - M);
    float L = l*e0 + l1*e1;
    float* dst;
    if (isLig) dst = partL + ((size_t)((qt*16+q)*8 + h)*8 + slice)*18;
    else       dst = partP + ((size_t)((qt*16+q)*8 + h)*4 + slice)*18;
    dst[0] = M; dst[1] = L;
    dst[2]  = O0.x*e0 + b[2]*e1;  dst[3]  = O0.y*e0 + b[3]*e1;
    dst[4]  = O0.z*e0 + b[4]*e1;  dst[5]  = O0.w*e0 + b[5]*e1;
    dst[6]  = O1.x*e0 + b[6]*e1;  dst[7]  = O1.y*e0 + b[7]*e1;
    dst[8]  = O1.z*e0 + b[8]*e1;  dst[9]  = O1.w*e0 + b[9]*e1;
    dst[10] = O2.x*e0 + b[10]*e1; dst[11] = O2.y*e0 + b[11]*e1;
    dst[12] = O2.z*e0 + b[12]*e1; dst[13] = O2.w*e0 + b[13]*e1;
    dst[14] = O3.x*e0 + b[14]*e1; dst[15] = O3.y*e0 + b[15]*e1;
    dst[16] = O3.z*e0 + b[16]*e1; dst[17] = O3.w*e0 + b[17]*e1;
  }
}

// ---------------- merge partials + Wo proj + residual + LayerNorm ----------------
__global__ __launch_bounds__(128) void merge_ln(const float* __restrict__ partL, const float* __restrict__ partP,
                                                const float* __restrict__ lenh, const float* __restrict__ penh,
                                                const float* __restrict__ Wo, const float* __restrict__ bo,
                                                const float* __restrict__ g_l, const float* __restrict__ be_l,
                                                const float* __restrict__ g_p, const float* __restrict__ be_p,
                                                float* __restrict__ out){
  int r = blockIdx.x, t = threadIdx.x;
  int h = t >> 4, c = t & 15;
  int ns; const float* base;
  if (r < NL){ ns = 8; base = partL + ((size_t)(r*8 + h))*8*18; }
  else       { ns = 4; base = partP + ((size_t)((r-NL)*8 + h))*4*18; }
  float M = -1e30f;
  for (int s = 0; s < ns; s++) M = fmaxf(M, base[s*18]);
  float Lsum = 0.f, Osum = 0.f;
  for (int s = 0; s < ns; s++){
    float e = __expf(base[s*18] - M);
    Lsum = fmaf(e, base[s*18+1], Lsum);
    Osum = fmaf(e, base[s*18+2+c], Osum);
  }
  __shared__ float satt[HDIM];
  satt[t] = Osum / Lsum;
  __syncthreads();
  float o = bo[t];
  const float4* wr = (const float4*)(Wo + (size_t)t*HDIM);
  const float4* sv = (const float4*)satt;
  #pragma unroll 8
  for (int k = 0; k < 32; k++) o += dot4f(wr[k], sv[k]);
  const float* enh = (r < NL) ? (lenh + (size_t)r*HDIM) : (penh + (size_t)(r-NL)*HDIM);
  float x = enh[t] + o;
  __shared__ float red[HDIM];
  red[t] = x; __syncthreads();
  #pragma unroll
  for (int s = 64; s > 0; s >>= 1){ if (t < s) red[t] += red[t+s]; __syncthreads(); }
  float mu = red[0] * (1.f/128.f); __syncthreads();
  float dx = x - mu;
  red[t] = dx*dx; __syncthreads();
  #pragma unroll
  for (int s = 64; s > 0; s >>= 1){ if (t < s) red[t] += red[t+s]; __syncthreads(); }
  float var = red[0] * (1.f/128.f);
  float y = dx * rsqrtf(var + 1e-5f);
  if (r < NL){
    y = fmaf(y, g_l[t], be_l[t]);
    out[(size_t)r*HDIM + t] = y;
  } else {
    y = fmaf(y, g_p[t], be_p[t]);
    out[(size_t)NL*HDIM + (size_t)(r-NL)*HDIM + t] = y;
  }
}

extern "C" void kernel_launch(void* const* d_in, const int* in_sizes, int n_in,
                              void* d_out, int out_size, void* d_ws, size_t ws_size,
                              hipStream_t stream){
  const float* lf   = (const float*)d_in[0];
  const float* pf   = (const float*)d_in[1];
  const float* lc   = (const float*)d_in[2];
  const float* pc   = (const float*)d_in[3];
  const float* Wl   = (const float*)d_in[4];
  const float* bl   = (const float*)d_in[5];
  const float* Wp   = (const float*)d_in[6];
  const float* bp   = (const float*)d_in[7];
  const float* Wd1  = (const float*)d_in[8];
  const float* bd1  = (const float*)d_in[9];
  const float* Wd2  = (const float*)d_in[10];
  const float* bd2  = (const float*)d_in[11];
  const float* Wd3  = (const float*)d_in[12];
  const float* bd3  = (const float*)d_in[13];
  const float* Wgl  = (const float*)d_in[14];
  const float* bgl  = (const float*)d_in[15];
  const float* Wgp  = (const float*)d_in[16];
  const float* bgp  = (const float*)d_in[17];
  const float* Wqkv = (const float*)d_in[18];
  const float* bqkv = (const float*)d_in[19];
  const float* Wo   = (const float*)d_in[20];
  const float* bo   = (const float*)d_in[21];
  const float* g_l  = (const float*)d_in[22];
  const float* be_l = (const float*)d_in[23];
  const float* g_p  = (const float*)d_in[24];
  const float* be_p = (const float*)d_in[25];

  float* ws  = (float*)d_ws;
  float* out = (float*)d_out;
  float* wsw   = ws + WD3M_OFF;
  float* mws   = ws + M_OFF;
  float* lig   = ws + LIG_OFF;
  float* poc   = ws + POC_OFF;
  float* lenh  = ws + LENH_OFF;
  float* penh  = ws + PENH_OFF;
  float* qkvl  = ws + QKVL_OFF;
  float* qkvp  = ws + QKVP_OFF;
  float* partL = ws + PARTL_OFF;
  float* partP = ws + PARTP_OFF;
  float* tab   = ws + TAB_OFF;   // aliases qkvl region; consumed before qkv_kernel writes

  prep_kernel<<<1, 128, 0, stream>>>(Wd3, bd3, wsw);
  table_kernel<<<TAB_N/256, 256, 0, stream>>>(Wd1, bd1, Wd2, bd2, wsw, tab);
  proj_kernel<<<384, 128, 0, stream>>>(lf, pf, Wl, bl, Wp, bp, lig, poc);
  m_lut_kernel<<<NL, 256, 0, stream>>>(lc, pc, tab, mws);
  agg_gate_fused<<<NL + NP, 1024, 0, stream>>>(mws, lig, poc, Wgl, bgl, Wgp, bgp, lenh, penh);
  qkv_kernel<<<384, 384, 0, stream>>>(lenh, penh, Wqkv, bqkv, qkvl, qkvp);
  attn_part<<<512, 256, 0, stream>>>(qkvl, qkvp, partL, partP);
  merge_ln<<<1536, 128, 0, stream>>>(partL, partP, lenh, penh, Wo, bo, g_l, be_l, g_p, be_p, out);
}

// Round 5
// 233.401 us; speedup vs baseline: 1.6242x; 1.0154x over previous
//
#include <hip/hip_runtime.h>
#include <math.h>

#define NL 512
#define NP 1024
#define HDIM 128

#define TAB_N 8192
#define DMAX 34.65f

// ---- workspace layout (float offsets) ----
#define WD3M_OFF 0                            // 64 col-means of Wd3 + bd3 mean at [64]
#define M_OFF    128                          // (free since R5 fusion)
#define LIG_OFF  (M_OFF + NL*NP)              // lig proj 512x128
#define POC_OFF  (LIG_OFF + NL*HDIM)          // poc proj 1024x128
#define LENH_OFF (POC_OFF + NP*HDIM)          // lig_enh 512x128
#define PENH_OFF (LENH_OFF + NL*HDIM)         // poc_enh 1024x128
#define QKVL_OFF (PENH_OFF + NP*HDIM)         // qkv for lig_enh 512x384  (aliased by m(d) table earlier)
#define QKVP_OFF (QKVL_OFF + NL*384)          // qkv for poc_enh 1024x384
#define PARTL_OFF (QKVP_OFF + NP*384)         // lig partials: [512][8 h][8 slices][18]
#define PARTP_OFF (PARTL_OFF + 512*8*8*18)    // poc partials: [1024][8 h][4 slices][18]
#define TAB_OFF  QKVL_OFF                     // table consumed by agg_gate before qkv_kernel writes here

__device__ __forceinline__ float dot4f(float4 a, float4 b){
  return fmaf(a.x,b.x, fmaf(a.y,b.y, fmaf(a.z,b.z, a.w*b.w)));
}

// ---------------- prep: wd3m[k] = mean_i Wd3[i][k]; wd3m[64] = mean(bd3) ----------------
__global__ __launch_bounds__(128) void prep_kernel(const float* __restrict__ Wd3,
                                                   const float* __restrict__ bd3,
                                                   float* __restrict__ wsw){
  int t = threadIdx.x;
  if (t < 64){
    float s = 0.f;
    #pragma unroll 8
    for (int i = 0; i < 128; i++) s += Wd3[i*64 + t];
    wsw[t] = s * (1.f/128.f);
  } else if (t == 64){
    float s = 0.f;
    for (int i = 0; i < 128; i++) s += bd3[i];
    wsw[64] = s * (1.f/128.f);
  }
}

// ---------------- proj: lig = LF@Wl.T+bl ; poc = PF@Wp.T+bp (4 rows/block) ----------------
__global__ __launch_bounds__(128) void proj_kernel(const float* __restrict__ lf, const float* __restrict__ pf,
                                                   const float* __restrict__ Wl, const float* __restrict__ bl,
                                                   const float* __restrict__ Wp, const float* __restrict__ bp,
                                                   float* __restrict__ lig, float* __restrict__ poc){
  int t = threadIdx.x;
  int row0 = blockIdx.x * 4;
  const float* in; const float* W; const float* bias; float* out;
  if (row0 < NL){ in = lf + (size_t)row0*HDIM; W = Wl; bias = bl; out = lig + (size_t)row0*HDIM; }
  else { int r = row0 - NL; in = pf + (size_t)r*HDIM; W = Wp; bias = bp; out = poc + (size_t)r*HDIM; }
  __shared__ float sin[4*HDIM];
  for (int idx = t; idx < 4*HDIM; idx += 128) sin[idx] = in[idx];
  __syncthreads();
  float bv = bias[t];
  float a0 = bv, a1 = bv, a2 = bv, a3 = bv;
  const float4* wr = (const float4*)(W + (size_t)t*HDIM);
  const float4* s0 = (const float4*)(sin);
  const float4* s1 = (const float4*)(sin + HDIM);
  const float4* s2 = (const float4*)(sin + 2*HDIM);
  const float4* s3 = (const float4*)(sin + 3*HDIM);
  #pragma unroll 8
  for (int k = 0; k < 32; k++){
    float4 w = wr[k];
    a0 = fmaf(w.x, s0[k].x, fmaf(w.y, s0[k].y, fmaf(w.z, s0[k].z, fmaf(w.w, s0[k].w, a0))));
    a1 = fmaf(w.x, s1[k].x, fmaf(w.y, s1[k].y, fmaf(w.z, s1[k].z, fmaf(w.w, s1[k].w, a1))));
    a2 = fmaf(w.x, s2[k].x, fmaf(w.y, s2[k].y, fmaf(w.z, s2[k].z, fmaf(w.w, s2[k].w, a2))));
    a3 = fmaf(w.x, s3[k].x, fmaf(w.y, s3[k].y, fmaf(w.z, s3[k].z, fmaf(w.w, s3[k].w, a3))));
  }
  out[t] = a0; out[HDIM + t] = a1; out[2*HDIM + t] = a2; out[3*HDIM + t] = a3;
}

// ---------------- table: tab[idx] = m(idx * DMAX/(TAB_N-1)) via full MLP ----------------
__global__ __launch_bounds__(256) void table_kernel(const float* __restrict__ Wd1, const float* __restrict__ bd1,
                                                    const float* __restrict__ Wd2, const float* __restrict__ bd2,
                                                    const float* __restrict__ wsw, float* __restrict__ tab){
  __shared__ float sWd1[32], sbd1[32], sWd2[2048], sbd2[64], swd3m[64];
  __shared__ float sbd3m;
  int t = threadIdx.x;
  int idx = blockIdx.x * 256 + t;
  if (t < 32){ sWd1[t] = Wd1[t]; sbd1[t] = bd1[t]; }
  if (t >= 32 && t < 96){ sbd2[t-32] = bd2[t-32]; swd3m[t-32] = wsw[t-32]; }
  if (t == 96) sbd3m = wsw[64];
  for (int k = t; k < 2048; k += 256) sWd2[k] = Wd2[k];
  __syncthreads();

  float d = (float)idx * (DMAX / (float)(TAB_N - 1));

  float4 e1q[8];
  const float4* w1q = (const float4*)sWd1;
  const float4* b1q = (const float4*)sbd1;
  #pragma unroll
  for (int k4 = 0; k4 < 8; k4++){
    float4 w = w1q[k4], b = b1q[k4];
    float4 e;
    e.x = fmaxf(fmaf(d, w.x, b.x), 0.f);
    e.y = fmaxf(fmaf(d, w.y, b.y), 0.f);
    e.z = fmaxf(fmaf(d, w.z, b.z), 0.f);
    e.w = fmaxf(fmaf(d, w.w, b.w), 0.f);
    e1q[k4] = e;
  }
  float mv = sbd3m;
  #pragma unroll 4
  for (int j2 = 0; j2 < 64; j2++){
    const float4* wrow = (const float4*)(sWd2 + j2*32);
    float a0 = 0.f, a1 = 0.f, a2 = 0.f, a3 = 0.f;
    #pragma unroll
    for (int k4 = 0; k4 < 8; k4++){
      float4 w = wrow[k4], e = e1q[k4];
      a0 = fmaf(w.x, e.x, a0);
      a1 = fmaf(w.y, e.y, a1);
      a2 = fmaf(w.z, e.z, a2);
      a3 = fmaf(w.w, e.w, a3);
    }
    float e2v = fmaxf(sbd2[j2] + ((a0+a1)+(a2+a3)), 0.f);
    mv = fmaf(swd3m[j2], e2v, mv);
  }
  tab[idx] = mv;
}

// ---------------- fused: inline dist+LUT -> softmax -> aggregation -> gate, both directions ----------------
// grid = NL+NP blocks x 1024 threads.
// Block r<NL: ligand row r (n=1024 partners); else pocket row j=r-NL (n=512 partners).
__global__ __launch_bounds__(1024) void agg_gate_fused(const float* __restrict__ lc, const float* __restrict__ pc,
                                                       const float* __restrict__ tab,
                                                       const float* __restrict__ lig, const float* __restrict__ poc,
                                                       const float* __restrict__ Wgl, const float* __restrict__ bgl,
                                                       const float* __restrict__ Wgp, const float* __restrict__ bgp,
                                                       float* __restrict__ lenh, float* __restrict__ penh){
  int r = blockIdx.x, t = threadIdx.x;
  __shared__ float stab[TAB_N];        // 32 KB
  __shared__ float w[NP];              // 4 KB
  __shared__ float red[20];
  __shared__ float part[4096];         // 16 KB: [32 jg][128 col]
  __shared__ float sx[HDIM], sa[HDIM];
  __shared__ float gpart[512];
  bool isLig = (r < NL);
  int n = isLig ? NP : NL;
  int rloc = isLig ? r : (r - NL);

  // stage table (2 float4 per thread)
  for (int k = t; k < TAB_N/4; k += 1024) ((float4*)stab)[k] = ((const float4*)tab)[k];

  // own coordinate (block-uniform) + partner coordinate (per-thread) — overlap with staging
  const float* ccoord = isLig ? (lc + rloc*3) : (pc + rloc*3);
  float cx = ccoord[0], cy = ccoord[1], cz = ccoord[2];
  bool active = t < n;
  float ox = 0.f, oy = 0.f, oz = 0.f;
  if (active){
    const float* oc = isLig ? (pc + t*3) : (lc + t*3);
    ox = oc[0]; oy = oc[1]; oz = oc[2];
  }
  // own feature row into sx
  if (t < HDIM) sx[t] = isLig ? lig[(size_t)rloc*HDIM + t] : poc[(size_t)rloc*HDIM + t];
  __syncthreads();   // table ready

  float x = -1e30f;
  if (active){
    float dx = cx-ox, dy = cy-oy, dz = cz-oz;
    float d = sqrtf(fmaf(dx,dx, fmaf(dy,dy, dz*dz)));
    float xf = d * ((float)(TAB_N-1)/DMAX);
    int i0 = (int)xf;
    i0 = (i0 > TAB_N-2) ? (TAB_N-2) : i0;
    float f = xf - (float)i0;
    float v0 = stab[i0], v1 = stab[i0+1];
    x = -fmaf(f, v1 - v0, v0);
  }

  // block max
  float v = x;
  #pragma unroll
  for (int off = 32; off; off >>= 1) v = fmaxf(v, __shfl_down(v, off));
  int wid = t >> 6, lane = t & 63;
  if (lane == 0) red[wid] = v;
  __syncthreads();
  if (t == 0){ float mm = red[0]; for (int k = 1; k < 16; k++) mm = fmaxf(mm, red[k]); red[16] = mm; }
  __syncthreads();
  float mx = red[16];

  float e = active ? __expf(x - mx) : 0.f;
  w[t] = e;
  v = e;
  #pragma unroll
  for (int off = 32; off; off >>= 1) v += __shfl_down(v, off);
  if (lane == 0) red[wid] = v;
  __syncthreads();
  if (t == 0){ float ss = 0.f; for (int k = 0; k < 16; k++) ss += red[k]; red[17] = 1.0f / ss; }
  __syncthreads();
  float inv = red[17];

  // aggregation: 32 j-groups x 32 float4-cols, coalesced 16B loads
  int jg = t >> 5, c4 = t & 31;
  int per = n >> 5;                  // 32 (lig) / 16 (poc)
  const float4* src4 = (const float4*)(isLig ? poc : lig);
  int j0 = jg * per;
  float4 acc = {0.f, 0.f, 0.f, 0.f};
  #pragma unroll 4
  for (int jj = 0; jj < per; jj++){
    int j = j0 + jj;
    float wj = w[j];
    float4 sv = src4[(size_t)j*32 + c4];
    acc.x = fmaf(wj, sv.x, acc.x);
    acc.y = fmaf(wj, sv.y, acc.y);
    acc.z = fmaf(wj, sv.z, acc.z);
    acc.w = fmaf(wj, sv.w, acc.w);
  }
  float4* p4 = (float4*)part;
  p4[jg*32 + c4] = acc;
  __syncthreads();
  #pragma unroll
  for (int s = 16; s >= 1; s >>= 1){
    if (jg < s){
      float4 a = p4[jg*32 + c4], b = p4[(jg+s)*32 + c4];
      a.x += b.x; a.y += b.y; a.z += b.z; a.w += b.w;
      p4[jg*32 + c4] = a;
    }
    __syncthreads();
  }
  if (t < 32){
    float4 a = p4[t];
    sa[t*4+0] = a.x*inv; sa[t*4+1] = a.y*inv; sa[t*4+2] = a.z*inv; sa[t*4+3] = a.w*inv;
  }
  __syncthreads();

  // gate: 4 k-quarters x 128 cols (512 threads)
  if (t < 512){
    int col = t & 127, qg = t >> 7;
    const float* Wg = isLig ? Wgl : Wgp;
    const float4* wr = (const float4*)(Wg + (size_t)col*256 + qg*64);
    const float4* inq = (qg < 2) ? ((const float4*)sx + qg*16) : ((const float4*)sa + (qg-2)*16);
    float g = 0.f;
    #pragma unroll
    for (int k = 0; k < 16; k++) g += dot4f(wr[k], inq[k]);
    gpart[qg*128 + col] = g;
  }
  __syncthreads();
  if (t < 128){
    const float* bg = isLig ? bgl : bgp;
    float g = bg[t] + ((gpart[t] + gpart[128+t]) + (gpart[256+t] + gpart[384+t]));
    g = 1.0f / (1.0f + __expf(-g));
    float* dst = isLig ? (lenh + (size_t)rloc*HDIM) : (penh + (size_t)rloc*HDIM);
    dst[t] = fmaf(g, sx[t] - sa[t], sa[t]);   // g*x + (1-g)*a
  }
}

// ---------------- qkv: [lig_enh; poc_enh] @ Wqkv.T + bqkv (4 rows/block, 384 threads) ----------------
__global__ __launch_bounds__(384) void qkv_kernel(const float* __restrict__ lenh, const float* __restrict__ penh,
                                                  const float* __restrict__ Wqkv, const float* __restrict__ bqkv,
                                                  float* __restrict__ qkvl, float* __restrict__ qkvp){
  int t = threadIdx.x;
  int row0 = blockIdx.x * 4;
  const float* in; float* out; int rloc;
  if (row0 < NL){ in = lenh + (size_t)row0*HDIM; out = qkvl; rloc = row0; }
  else { rloc = row0 - NL; in = penh + (size_t)rloc*HDIM; out = qkvp; }
  __shared__ float sin[4*HDIM];
  for (int idx = t; idx < 4*HDIM; idx += 384) sin[idx] = in[idx];
  __syncthreads();
  float bv = bqkv[t];
  float a0 = bv, a1 = bv, a2 = bv, a3 = bv;
  const float4* wr = (const float4*)(Wqkv + (size_t)t*HDIM);
  const float4* s0 = (const float4*)(sin);
  const float4* s1 = (const float4*)(sin + HDIM);
  const float4* s2 = (const float4*)(sin + 2*HDIM);
  const float4* s3 = (const float4*)(sin + 3*HDIM);
  #pragma unroll 8
  for (int k = 0; k < 32; k++){
    float4 w = wr[k];
    a0 = fmaf(w.x, s0[k].x, fmaf(w.y, s0[k].y, fmaf(w.z, s0[k].z, fmaf(w.w, s0[k].w, a0))));
    a1 = fmaf(w.x, s1[k].x, fmaf(w.y, s1[k].y, fmaf(w.z, s1[k].z, fmaf(w.w, s1[k].w, a1))));
    a2 = fmaf(w.x, s2[k].x, fmaf(w.y, s2[k].y, fmaf(w.z, s2[k].z, fmaf(w.w, s2[k].w, a2))));
    a3 = fmaf(w.x, s3[k].x, fmaf(w.y, s3[k].y, fmaf(w.z, s3[k].z, fmaf(w.w, s3[k].w, a3))));
  }
  out[(size_t)(rloc+0)*384 + t] = a0;
  out[(size_t)(rloc+1)*384 + t] = a1;
  out[(size_t)(rloc+2)*384 + t] = a2;
  out[(size_t)(rloc+3)*384 + t] = a3;
}

// ---------------- flash attention, v2 (h-major lanes; 2 split-k groups per block) ----------------
__global__ __launch_bounds__(256) void attn_part(const float* __restrict__ qkvl, const float* __restrict__ qkvp,
                                                 float* __restrict__ partL, float* __restrict__ partP){
  int bx = blockIdx.x;
  int t = threadIdx.x;
  const float* qsrc; const float* kvsrc; int qt, slice; bool isLig;
  if (bx < 256){ isLig = true;  qt = bx >> 3; slice = bx & 7; qsrc = qkvl; kvsrc = qkvp; }
  else { int b2 = bx - 256; isLig = false; qt = b2 >> 2; slice = b2 & 3; qsrc = qkvp; kvsrc = qkvl; }
  int g = t >> 7, tt = t & 127;
  int h = tt >> 4, q = tt & 15;
  int j0 = slice*128 + g*64;

  const float4* qp = (const float4*)(qsrc + (size_t)(qt*16+q)*384 + h*16);
  float4 q0 = qp[0], q1 = qp[1], q2 = qp[2], q3 = qp[3];
  float m = -1e30f, l = 0.f;
  float4 O0 = {0,0,0,0}, O1 = {0,0,0,0}, O2 = {0,0,0,0}, O3 = {0,0,0,0};

  __shared__ float sKV[8192];
  float* myKV = sKV + g*4096;

  for (int tile = 0; tile < 4; tile++){
    int jbase = j0 + tile*16;
    __syncthreads();
    #pragma unroll
    for (int n = 0; n < 8; n++){
      int v4 = tt + n*128;
      int jj = v4 >> 6, c4 = v4 & 63;
      ((float4*)myKV)[(size_t)jj*64 + c4] = *(const float4*)(kvsrc + (size_t)(jbase+jj)*384 + 128 + c4*4);
    }
    __syncthreads();
    float s[16];
    #pragma unroll
    for (int jj = 0; jj < 16; jj++){
      const float4* kk = (const float4*)(myKV + jj*256 + h*16);
      s[jj] = (dot4f(q0, kk[0]) + dot4f(q1, kk[1]) + dot4f(q2, kk[2]) + dot4f(q3, kk[3])) * 0.25f;
    }
    float mt = s[0];
    #pragma unroll
    for (int jj = 1; jj < 16; jj++) mt = fmaxf(mt, s[jj]);
    float mn = fmaxf(m, mt);
    float corr = __expf(m - mn);
    l *= corr;
    O0.x*=corr; O0.y*=corr; O0.z*=corr; O0.w*=corr;
    O1.x*=corr; O1.y*=corr; O1.z*=corr; O1.w*=corr;
    O2.x*=corr; O2.y*=corr; O2.z*=corr; O2.w*=corr;
    O3.x*=corr; O3.y*=corr; O3.z*=corr; O3.w*=corr;
    #pragma unroll
    for (int jj = 0; jj < 16; jj++){
      float p = __expf(s[jj] - mn);
      l += p;
      const float4* vv = (const float4*)(myKV + jj*256 + 128 + h*16);
      O0.x = fmaf(p, vv[0].x, O0.x); O0.y = fmaf(p, vv[0].y, O0.y);
      O0.z = fmaf(p, vv[0].z, O0.z); O0.w = fmaf(p, vv[0].w, O0.w);
      O1.x = fmaf(p, vv[1].x, O1.x); O1.y = fmaf(p, vv[1].y, O1.y);
      O1.z = fmaf(p, vv[1].z, O1.z); O1.w = fmaf(p, vv[1].w, O1.w);
      O2.x = fmaf(p, vv[2].x, O2.x); O2.y = fmaf(p, vv[2].y, O2.y);
      O2.z = fmaf(p, vv[2].z, O2.z); O2.w = fmaf(p, vv[2].w, O2.w);
      O3.x = fmaf(p, vv[3].x, O3.x); O3.y = fmaf(p, vv[3].y, O3.y);
      O3.z = fmaf(p, vv[3].z, O3.z); O3.w = fmaf(p, vv[3].w, O3.w);
    }
    m = mn;
  }

  __syncthreads();
  float* smerge = sKV;
  if (g == 1){
    float* b = smerge + tt*19;
    b[0] = m; b[1] = l;
    b[2]=O0.x; b[3]=O0.y; b[4]=O0.z; b[5]=O0.w;
    b[6]=O1.x; b[7]=O1.y; b[8]=O1.z; b[9]=O1.w;
    b[10]=O2.x; b[11]=O2.y; b[12]=O2.z; b[13]=O2.w;
    b[14]=O3.x; b[15]=O3.y; b[16]=O3.z; b[17]=O3.w;
  }
  __syncthreads();
  if (g == 0){
    const float* b = smerge + tt*19;
    float m1 = b[0], l1 = b[1];
    float M = fmaxf(m, m1);
    float e0 = __expf(m - M), e1 = __expf(m1 - M);
    float L = l*e0 + l1*e1;
    float* dst;
    if (isLig) dst = partL + ((size_t)((qt*16+q)*8 + h)*8 + slice)*18;
    else       dst = partP + ((size_t)((qt*16+q)*8 + h)*4 + slice)*18;
    dst[0] = M; dst[1] = L;
    dst[2]  = O0.x*e0 + b[2]*e1;  dst[3]  = O0.y*e0 + b[3]*e1;
    dst[4]  = O0.z*e0 + b[4]*e1;  dst[5]  = O0.w*e0 + b[5]*e1;
    dst[6]  = O1.x*e0 + b[6]*e1;  dst[7]  = O1.y*e0 + b[7]*e1;
    dst[8]  = O1.z*e0 + b[8]*e1;  dst[9]  = O1.w*e0 + b[9]*e1;
    dst[10] = O2.x*e0 + b[10]*e1; dst[11] = O2.y*e0 + b[11]*e1;
    dst[12] = O2.z*e0 + b[12]*e1; dst[13] = O2.w*e0 + b[13]*e1;
    dst[14] = O3.x*e0 + b[14]*e1; dst[15] = O3.y*e0 + b[15]*e1;
    dst[16] = O3.z*e0 + b[16]*e1; dst[17] = O3.w*e0 + b[17]*e1;
  }
}

// ---------------- merge partials + Wo proj + residual + LayerNorm ----------------
__global__ __launch_bounds__(128) void merge_ln(const float* __restrict__ partL, const float* __restrict__ partP,
                                                const float* __restrict__ lenh, const float* __restrict__ penh,
                                                const float* __restrict__ Wo, const float* __restrict__ bo,
                                                const float* __restrict__ g_l, const float* __restrict__ be_l,
                                                const float* __restrict__ g_p, const float* __restrict__ be_p,
                                                float* __restrict__ out){
  int r = blockIdx.x, t = threadIdx.x;
  int h = t >> 4, c = t & 15;
  int ns; const float* base;
  if (r < NL){ ns = 8; base = partL + ((size_t)(r*8 + h))*8*18; }
  else       { ns = 4; base = partP + ((size_t)((r-NL)*8 + h))*4*18; }
  float M = -1e30f;
  for (int s = 0; s < ns; s++) M = fmaxf(M, base[s*18]);
  float Lsum = 0.f, Osum = 0.f;
  for (int s = 0; s < ns; s++){
    float e = __expf(base[s*18] - M);
    Lsum = fmaf(e, base[s*18+1], Lsum);
    Osum = fmaf(e, base[s*18+2+c], Osum);
  }
  __shared__ float satt[HDIM];
  satt[t] = Osum / Lsum;
  __syncthreads();
  float o = bo[t];
  const float4* wr = (const float4*)(Wo + (size_t)t*HDIM);
  const float4* sv = (const float4*)satt;
  #pragma unroll 8
  for (int k = 0; k < 32; k++) o += dot4f(wr[k], sv[k]);
  const float* enh = (r < NL) ? (lenh + (size_t)r*HDIM) : (penh + (size_t)(r-NL)*HDIM);
  float x = enh[t] + o;
  __shared__ float red[HDIM];
  red[t] = x; __syncthreads();
  #pragma unroll
  for (int s = 64; s > 0; s >>= 1){ if (t < s) red[t] += red[t+s]; __syncthreads(); }
  float mu = red[0] * (1.f/128.f); __syncthreads();
  float dx = x - mu;
  red[t] = dx*dx; __syncthreads();
  #pragma unroll
  for (int s = 64; s > 0; s >>= 1){ if (t < s) red[t] += red[t+s]; __syncthreads(); }
  float var = red[0] * (1.f/128.f);
  float y = dx * rsqrtf(var + 1e-5f);
  if (r < NL){
    y = fmaf(y, g_l[t], be_l[t]);
    out[(size_t)r*HDIM + t] = y;
  } else {
    y = fmaf(y, g_p[t], be_p[t]);
    out[(size_t)NL*HDIM + (size_t)(r-NL)*HDIM + t] = y;
  }
}

extern "C" void kernel_launch(void* const* d_in, const int* in_sizes, int n_in,
                              void* d_out, int out_size, void* d_ws, size_t ws_size,
                              hipStream_t stream){
  const float* lf   = (const float*)d_in[0];
  const float* pf   = (const float*)d_in[1];
  const float* lc   = (const float*)d_in[2];
  const float* pc   = (const float*)d_in[3];
  const float* Wl   = (const float*)d_in[4];
  const float* bl   = (const float*)d_in[5];
  const float* Wp   = (const float*)d_in[6];
  const float* bp   = (const float*)d_in[7];
  const float* Wd1  = (const float*)d_in[8];
  const float* bd1  = (const float*)d_in[9];
  const float* Wd2  = (const float*)d_in[10];
  const float* bd2  = (const float*)d_in[11];
  const float* Wd3  = (const float*)d_in[12];
  const float* bd3  = (const float*)d_in[13];
  const float* Wgl  = (const float*)d_in[14];
  const float* bgl  = (const float*)d_in[15];
  const float* Wgp  = (const float*)d_in[16];
  const float* bgp  = (const float*)d_in[17];
  const float* Wqkv = (const float*)d_in[18];
  const float* bqkv = (const float*)d_in[19];
  const float* Wo   = (const float*)d_in[20];
  const float* bo   = (const float*)d_in[21];
  const float* g_l  = (const float*)d_in[22];
  const float* be_l = (const float*)d_in[23];
  const float* g_p  = (const float*)d_in[24];
  const float* be_p = (const float*)d_in[25];

  float* ws  = (float*)d_ws;
  float* out = (float*)d_out;
  float* wsw   = ws + WD3M_OFF;
  float* lig   = ws + LIG_OFF;
  float* poc   = ws + POC_OFF;
  float* lenh  = ws + LENH_OFF;
  float* penh  = ws + PENH_OFF;
  float* qkvl  = ws + QKVL_OFF;
  float* qkvp  = ws + QKVP_OFF;
  float* partL = ws + PARTL_OFF;
  float* partP = ws + PARTP_OFF;
  float* tab   = ws + TAB_OFF;   // aliases qkvl region; consumed before qkv_kernel writes

  prep_kernel<<<1, 128, 0, stream>>>(Wd3, bd3, wsw);
  table_kernel<<<TAB_N/256, 256, 0, stream>>>(Wd1, bd1, Wd2, bd2, wsw, tab);
  proj_kernel<<<384, 128, 0, stream>>>(lf, pf, Wl, bl, Wp, bp, lig, poc);
  agg_gate_fused<<<NL + NP, 1024, 0, stream>>>(lc, pc, tab, lig, poc, Wgl, bgl, Wgp, bgp, lenh, penh);
  qkv_kernel<<<384, 384, 0, stream>>>(lenh, penh, Wqkv, bqkv, qkvl, qkvp);
  attn_part<<<512, 256, 0, stream>>>(qkvl, qkvp, partL, partP);
  merge_ln<<<1536, 128, 0, stream>>>(partL, partP, lenh, penh, Wo, bo, g_l, be_l, g_p, be_p, out);
}

// Round 6
// 232.676 us; speedup vs baseline: 1.6292x; 1.0031x over previous
//
#include <hip/hip_runtime.h>
#include <math.h>

#define NL 512
#define NP 1024
#define HDIM 128

#define TAB_N 8192
#define DMAX 34.65f

// ---- workspace layout (float offsets) ----
#define WD3M_OFF 0                            // 64 col-means of Wd3 + bd3 mean at [64]
#define M_OFF    128                          // (free)
#define LIG_OFF  (M_OFF + NL*NP)              // lig proj 512x128
#define POC_OFF  (LIG_OFF + NL*HDIM)          // poc proj 1024x128
#define LENH_OFF (POC_OFF + NP*HDIM)          // lig_enh 512x128
#define PENH_OFF (LENH_OFF + NL*HDIM)         // poc_enh 1024x128
#define QKVL_OFF (PENH_OFF + NP*HDIM)         // qkv for lig_enh 512x384  (aliased by m(d) table earlier)
#define QKVP_OFF (QKVL_OFF + NL*384)          // qkv for poc_enh 1024x384
#define PARTL_OFF (QKVP_OFF + NP*384)         // lig partials: [512][8 h][8 slices][18]
#define PARTP_OFF (PARTL_OFF + 512*8*8*18)    // poc partials: [1024][8 h][4 slices][18]
#define TAB_OFF  QKVL_OFF                     // table consumed by agg_gate before qkv_kernel writes here

__device__ __forceinline__ float dot4f(float4 a, float4 b){
  return fmaf(a.x,b.x, fmaf(a.y,b.y, fmaf(a.z,b.z, a.w*b.w)));
}

// ---------------- prep: wd3m[k] = mean_i Wd3[i][k]; wd3m[64] = mean(bd3) ----------------
__global__ __launch_bounds__(128) void prep_kernel(const float* __restrict__ Wd3,
                                                   const float* __restrict__ bd3,
                                                   float* __restrict__ wsw){
  int t = threadIdx.x;
  if (t < 64){
    float s = 0.f;
    #pragma unroll 8
    for (int i = 0; i < 128; i++) s += Wd3[i*64 + t];
    wsw[t] = s * (1.f/128.f);
  } else if (t == 64){
    float s = 0.f;
    for (int i = 0; i < 128; i++) s += bd3[i];
    wsw[64] = s * (1.f/128.f);
  }
}

// ---------------- proj: lig = LF@Wl.T+bl ; poc = PF@Wp.T+bp (4 rows/block) ----------------
__global__ __launch_bounds__(128) void proj_kernel(const float* __restrict__ lf, const float* __restrict__ pf,
                                                   const float* __restrict__ Wl, const float* __restrict__ bl,
                                                   const float* __restrict__ Wp, const float* __restrict__ bp,
                                                   float* __restrict__ lig, float* __restrict__ poc){
  int t = threadIdx.x;
  int row0 = blockIdx.x * 4;
  const float* in; const float* W; const float* bias; float* out;
  if (row0 < NL){ in = lf + (size_t)row0*HDIM; W = Wl; bias = bl; out = lig + (size_t)row0*HDIM; }
  else { int r = row0 - NL; in = pf + (size_t)r*HDIM; W = Wp; bias = bp; out = poc + (size_t)r*HDIM; }
  __shared__ float sin[4*HDIM];
  for (int idx = t; idx < 4*HDIM; idx += 128) sin[idx] = in[idx];
  __syncthreads();
  float bv = bias[t];
  float a0 = bv, a1 = bv, a2 = bv, a3 = bv;
  const float4* wr = (const float4*)(W + (size_t)t*HDIM);
  const float4* s0 = (const float4*)(sin);
  const float4* s1 = (const float4*)(sin + HDIM);
  const float4* s2 = (const float4*)(sin + 2*HDIM);
  const float4* s3 = (const float4*)(sin + 3*HDIM);
  #pragma unroll 8
  for (int k = 0; k < 32; k++){
    float4 w = wr[k];
    a0 = fmaf(w.x, s0[k].x, fmaf(w.y, s0[k].y, fmaf(w.z, s0[k].z, fmaf(w.w, s0[k].w, a0))));
    a1 = fmaf(w.x, s1[k].x, fmaf(w.y, s1[k].y, fmaf(w.z, s1[k].z, fmaf(w.w, s1[k].w, a1))));
    a2 = fmaf(w.x, s2[k].x, fmaf(w.y, s2[k].y, fmaf(w.z, s2[k].z, fmaf(w.w, s2[k].w, a2))));
    a3 = fmaf(w.x, s3[k].x, fmaf(w.y, s3[k].y, fmaf(w.z, s3[k].z, fmaf(w.w, s3[k].w, a3))));
  }
  out[t] = a0; out[HDIM + t] = a1; out[2*HDIM + t] = a2; out[3*HDIM + t] = a3;
}

// ---------------- table: tab[idx] = m(idx * DMAX/(TAB_N-1)) via full MLP ----------------
__global__ __launch_bounds__(256) void table_kernel(const float* __restrict__ Wd1, const float* __restrict__ bd1,
                                                    const float* __restrict__ Wd2, const float* __restrict__ bd2,
                                                    const float* __restrict__ wsw, float* __restrict__ tab){
  __shared__ float sWd1[32], sbd1[32], sWd2[2048], sbd2[64], swd3m[64];
  __shared__ float sbd3m;
  int t = threadIdx.x;
  int idx = blockIdx.x * 256 + t;
  if (t < 32){ sWd1[t] = Wd1[t]; sbd1[t] = bd1[t]; }
  if (t >= 32 && t < 96){ sbd2[t-32] = bd2[t-32]; swd3m[t-32] = wsw[t-32]; }
  if (t == 96) sbd3m = wsw[64];
  for (int k = t; k < 2048; k += 256) sWd2[k] = Wd2[k];
  __syncthreads();

  float d = (float)idx * (DMAX / (float)(TAB_N - 1));

  float4 e1q[8];
  const float4* w1q = (const float4*)sWd1;
  const float4* b1q = (const float4*)sbd1;
  #pragma unroll
  for (int k4 = 0; k4 < 8; k4++){
    float4 w = w1q[k4], b = b1q[k4];
    float4 e;
    e.x = fmaxf(fmaf(d, w.x, b.x), 0.f);
    e.y = fmaxf(fmaf(d, w.y, b.y), 0.f);
    e.z = fmaxf(fmaf(d, w.z, b.z), 0.f);
    e.w = fmaxf(fmaf(d, w.w, b.w), 0.f);
    e1q[k4] = e;
  }
  float mv = sbd3m;
  #pragma unroll 4
  for (int j2 = 0; j2 < 64; j2++){
    const float4* wrow = (const float4*)(sWd2 + j2*32);
    float a0 = 0.f, a1 = 0.f, a2 = 0.f, a3 = 0.f;
    #pragma unroll
    for (int k4 = 0; k4 < 8; k4++){
      float4 w = wrow[k4], e = e1q[k4];
      a0 = fmaf(w.x, e.x, a0);
      a1 = fmaf(w.y, e.y, a1);
      a2 = fmaf(w.z, e.z, a2);
      a3 = fmaf(w.w, e.w, a3);
    }
    float e2v = fmaxf(sbd2[j2] + ((a0+a1)+(a2+a3)), 0.f);
    mv = fmaf(swd3m[j2], e2v, mv);
  }
  tab[idx] = mv;
}

// ---------------- fused agg+gate, 4 rows per block ----------------
// grid = NL/4 + NP/4 = 384 blocks x 1024 threads.
// Phase A: softmax weights for 4 rows (4 groups of 256 threads; LUT gathered via L1).
// Phase B: aggregation GEMM 4x{n}x128 with feature reuse (8 jg x 128 cols).
// Phase C: gate matvec for 4 rows sharing Wg lines via L1.
__global__ __launch_bounds__(1024) void agg_gate_fused(const float* __restrict__ lc, const float* __restrict__ pc,
                                                       const float* __restrict__ tab,
                                                       const float* __restrict__ lig, const float* __restrict__ poc,
                                                       const float* __restrict__ Wgl, const float* __restrict__ bgl,
                                                       const float* __restrict__ Wgp, const float* __restrict__ bgp,
                                                       float* __restrict__ lenh, float* __restrict__ penh){
  int b = blockIdx.x, t = threadIdx.x;
  bool isLig = (b < NL/4);
  int r0 = isLig ? b*4 : (b - NL/4)*4;
  int n = isLig ? NP : NL;
  const float* myFeat = isLig ? lig : poc;
  const float* otherFeat = isLig ? poc : lig;
  const float* myC = isLig ? lc : pc;
  const float* otC = isLig ? pc : lc;

  __shared__ float w[4*NP];          // 16 KB softmax weights (rows x partners)
  __shared__ float sx[4*HDIM];       // own features
  __shared__ float sa[4*HDIM];       // aggregated features
  __shared__ float part[8*512];      // 16 KB agg partials [jg][r][c]
  __shared__ float gpart[4*2*128];   // 4 KB gate partials
  __shared__ float redm[16];
  __shared__ float sgm[4], sinv[4];

  int rr = t >> 8, u = t & 255;
  int lane = t & 63, wv = t >> 6;
  int row = r0 + rr;

  if (t < 512) sx[t] = myFeat[(size_t)r0*HDIM + t];

  float cx = myC[row*3+0], cy = myC[row*3+1], cz = myC[row*3+2];
  const float inv_h = (float)(TAB_N - 1) / DMAX;
  int per = n >> 8;                  // 4 (lig) or 2 (poc)

  // ---- Phase A: softmax over partners, per row ----
  float xs[4];
  float lmax = -1e30f;
  for (int k = 0; k < per; k++){
    int j = u + (k << 8);
    float ox = otC[j*3+0], oy = otC[j*3+1], oz = otC[j*3+2];
    float dx = cx-ox, dy = cy-oy, dz = cz-oz;
    float d = sqrtf(fmaf(dx,dx, fmaf(dy,dy, dz*dz)));
    float xf = d * inv_h;
    int i0 = (int)xf;
    i0 = (i0 > TAB_N-2) ? (TAB_N-2) : i0;
    float f = xf - (float)i0;
    float v0 = tab[i0], v1 = tab[i0+1];   // L1-resident 32 KB table
    xs[k] = -fmaf(f, v1 - v0, v0);
    lmax = fmaxf(lmax, xs[k]);
  }
  float v = lmax;
  #pragma unroll
  for (int off = 32; off; off >>= 1) v = fmaxf(v, __shfl_down(v, off));
  if (lane == 0) redm[wv] = v;
  __syncthreads();
  if (t < 4) sgm[t] = fmaxf(fmaxf(redm[t*4+0], redm[t*4+1]), fmaxf(redm[t*4+2], redm[t*4+3]));
  __syncthreads();
  float gm = sgm[rr];
  float lsum = 0.f;
  for (int k = 0; k < per; k++){
    float e = __expf(xs[k] - gm);
    w[rr*NP + u + (k << 8)] = e;
    lsum += e;
  }
  v = lsum;
  #pragma unroll
  for (int off = 32; off; off >>= 1) v += __shfl_down(v, off);
  if (lane == 0) redm[wv] = v;
  __syncthreads();
  if (t < 4) sinv[t] = 1.0f / ((redm[t*4+0] + redm[t*4+1]) + (redm[t*4+2] + redm[t*4+3]));
  __syncthreads();

  // ---- Phase B: aggregation (8 j-groups x 128 cols; j uniform per wave -> LDS broadcast) ----
  {
    int jg = t >> 7, cc = t & 127;
    int per2 = n >> 3;               // 128 (lig) / 64 (poc)
    int jb0 = jg * per2;
    float a0 = 0.f, a1 = 0.f, a2 = 0.f, a3 = 0.f;
    #pragma unroll 4
    for (int jj = 0; jj < per2; jj++){
      int j = jb0 + jj;
      float f = otherFeat[(size_t)j*HDIM + cc];
      a0 = fmaf(w[j], f, a0);
      a1 = fmaf(w[NP + j], f, a1);
      a2 = fmaf(w[2*NP + j], f, a2);
      a3 = fmaf(w[3*NP + j], f, a3);
    }
    part[jg*512 + 0*128 + cc] = a0;
    part[jg*512 + 1*128 + cc] = a1;
    part[jg*512 + 2*128 + cc] = a2;
    part[jg*512 + 3*128 + cc] = a3;
  }
  __syncthreads();
  #pragma unroll
  for (int s = 4; s >= 1; s >>= 1){
    for (int e = t; e < s*512; e += 1024) part[e] += part[e + s*512];
    __syncthreads();
  }
  if (t < 512){
    int r = t >> 7;
    sa[t] = part[t] * sinv[r];
  }
  __syncthreads();

  // ---- Phase C: gate (4 rows x 2 k-halves x 128 cols) ----
  {
    int r = t >> 8;                  // row
    int kg = (t >> 7) & 1;           // which half of the 256-wide input
    int col = t & 127;
    const float* Wg = isLig ? Wgl : Wgp;
    const float4* wr = (const float4*)(Wg + (size_t)col*256 + kg*128);
    const float4* inq = (kg == 0) ? (const float4*)(sx + r*128) : (const float4*)(sa + r*128);
    float g = 0.f;
    #pragma unroll 8
    for (int k = 0; k < 32; k++) g += dot4f(wr[k], inq[k]);
    gpart[r*256 + kg*128 + col] = g;
  }
  __syncthreads();
  if (t < 512){
    int r = t >> 7, c = t & 127;
    const float* bg = isLig ? bgl : bgp;
    float g = bg[c] + gpart[r*256 + c] + gpart[r*256 + 128 + c];
    g = 1.0f / (1.0f + __expf(-g));
    float xv = sx[r*128 + c], av = sa[r*128 + c];
    float* dst = isLig ? (lenh + (size_t)(r0+r)*HDIM) : (penh + (size_t)(r0+r)*HDIM);
    dst[c] = fmaf(g, xv - av, av);   // g*x + (1-g)*a
  }
}

// ---------------- qkv: [lig_enh; poc_enh] @ Wqkv.T + bqkv (4 rows/block, 384 threads) ----------------
__global__ __launch_bounds__(384) void qkv_kernel(const float* __restrict__ lenh, const float* __restrict__ penh,
                                                  const float* __restrict__ Wqkv, const float* __restrict__ bqkv,
                                                  float* __restrict__ qkvl, float* __restrict__ qkvp){
  int t = threadIdx.x;
  int row0 = blockIdx.x * 4;
  const float* in; float* out; int rloc;
  if (row0 < NL){ in = lenh + (size_t)row0*HDIM; out = qkvl; rloc = row0; }
  else { rloc = row0 - NL; in = penh + (size_t)rloc*HDIM; out = qkvp; }
  __shared__ float sin[4*HDIM];
  for (int idx = t; idx < 4*HDIM; idx += 384) sin[idx] = in[idx];
  __syncthreads();
  float bv = bqkv[t];
  float a0 = bv, a1 = bv, a2 = bv, a3 = bv;
  const float4* wr = (const float4*)(Wqkv + (size_t)t*HDIM);
  const float4* s0 = (const float4*)(sin);
  const float4* s1 = (const float4*)(sin + HDIM);
  const float4* s2 = (const float4*)(sin + 2*HDIM);
  const float4* s3 = (const float4*)(sin + 3*HDIM);
  #pragma unroll 8
  for (int k = 0; k < 32; k++){
    float4 w = wr[k];
    a0 = fmaf(w.x, s0[k].x, fmaf(w.y, s0[k].y, fmaf(w.z, s0[k].z, fmaf(w.w, s0[k].w, a0))));
    a1 = fmaf(w.x, s1[k].x, fmaf(w.y, s1[k].y, fmaf(w.z, s1[k].z, fmaf(w.w, s1[k].w, a1))));
    a2 = fmaf(w.x, s2[k].x, fmaf(w.y, s2[k].y, fmaf(w.z, s2[k].z, fmaf(w.w, s2[k].w, a2))));
    a3 = fmaf(w.x, s3[k].x, fmaf(w.y, s3[k].y, fmaf(w.z, s3[k].z, fmaf(w.w, s3[k].w, a3))));
  }
  out[(size_t)(rloc+0)*384 + t] = a0;
  out[(size_t)(rloc+1)*384 + t] = a1;
  out[(size_t)(rloc+2)*384 + t] = a2;
  out[(size_t)(rloc+3)*384 + t] = a3;
}

// ---------------- flash attention, v2 (h-major lanes; 2 split-k groups per block) ----------------
__global__ __launch_bounds__(256) void attn_part(const float* __restrict__ qkvl, const float* __restrict__ qkvp,
                                                 float* __restrict__ partL, float* __restrict__ partP){
  int bx = blockIdx.x;
  int t = threadIdx.x;
  const float* qsrc; const float* kvsrc; int qt, slice; bool isLig;
  if (bx < 256){ isLig = true;  qt = bx >> 3; slice = bx & 7; qsrc = qkvl; kvsrc = qkvp; }
  else { int b2 = bx - 256; isLig = false; qt = b2 >> 2; slice = b2 & 3; qsrc = qkvp; kvsrc = qkvl; }
  int g = t >> 7, tt = t & 127;
  int h = tt >> 4, q = tt & 15;
  int j0 = slice*128 + g*64;

  const float4* qp = (const float4*)(qsrc + (size_t)(qt*16+q)*384 + h*16);
  float4 q0 = qp[0], q1 = qp[1], q2 = qp[2], q3 = qp[3];
  float m = -1e30f, l = 0.f;
  float4 O0 = {0,0,0,0}, O1 = {0,0,0,0}, O2 = {0,0,0,0}, O3 = {0,0,0,0};

  __shared__ float sKV[8192];
  float* myKV = sKV + g*4096;

  for (int tile = 0; tile < 4; tile++){
    int jbase = j0 + tile*16;
    __syncthreads();
    #pragma unroll
    for (int n = 0; n < 8; n++){
      int v4 = tt + n*128;
      int jj = v4 >> 6, c4 = v4 & 63;
      ((float4*)myKV)[(size_t)jj*64 + c4] = *(const float4*)(kvsrc + (size_t)(jbase+jj)*384 + 128 + c4*4);
    }
    __syncthreads();
    float s[16];
    #pragma unroll
    for (int jj = 0; jj < 16; jj++){
      const float4* kk = (const float4*)(myKV + jj*256 + h*16);
      s[jj] = (dot4f(q0, kk[0]) + dot4f(q1, kk[1]) + dot4f(q2, kk[2]) + dot4f(q3, kk[3])) * 0.25f;
    }
    float mt = s[0];
    #pragma unroll
    for (int jj = 1; jj < 16; jj++) mt = fmaxf(mt, s[jj]);
    float mn = fmaxf(m, mt);
    float corr = __expf(m - mn);
    l *= corr;
    O0.x*=corr; O0.y*=corr; O0.z*=corr; O0.w*=corr;
    O1.x*=corr; O1.y*=corr; O1.z*=corr; O1.w*=corr;
    O2.x*=corr; O2.y*=corr; O2.z*=corr; O2.w*=corr;
    O3.x*=corr; O3.y*=corr; O3.z*=corr; O3.w*=corr;
    #pragma unroll
    for (int jj = 0; jj < 16; jj++){
      float p = __expf(s[jj] - mn);
      l += p;
      const float4* vv = (const float4*)(myKV + jj*256 + 128 + h*16);
      O0.x = fmaf(p, vv[0].x, O0.x); O0.y = fmaf(p, vv[0].y, O0.y);
      O0.z = fmaf(p, vv[0].z, O0.z); O0.w = fmaf(p, vv[0].w, O0.w);
      O1.x = fmaf(p, vv[1].x, O1.x); O1.y = fmaf(p, vv[1].y, O1.y);
      O1.z = fmaf(p, vv[1].z, O1.z); O1.w = fmaf(p, vv[1].w, O1.w);
      O2.x = fmaf(p, vv[2].x, O2.x); O2.y = fmaf(p, vv[2].y, O2.y);
      O2.z = fmaf(p, vv[2].z, O2.z); O2.w = fmaf(p, vv[2].w, O2.w);
      O3.x = fmaf(p, vv[3].x, O3.x); O3.y = fmaf(p, vv[3].y, O3.y);
      O3.z = fmaf(p, vv[3].z, O3.z); O3.w = fmaf(p, vv[3].w, O3.w);
    }
    m = mn;
  }

  __syncthreads();
  float* smerge = sKV;
  if (g == 1){
    float* b = smerge + tt*19;
    b[0] = m; b[1] = l;
    b[2]=O0.x; b[3]=O0.y; b[4]=O0.z; b[5]=O0.w;
    b[6]=O1.x; b[7]=O1.y; b[8]=O1.z; b[9]=O1.w;
    b[10]=O2.x; b[11]=O2.y; b[12]=O2.z; b[13]=O2.w;
    b[14]=O3.x; b[15]=O3.y; b[16]=O3.z; b[17]=O3.w;
  }
  __syncthreads();
  if (g == 0){
    const float* b = smerge + tt*19;
    float m1 = b[0], l1 = b[1];
    float M = fmaxf(m, m1);
    float e0 = __expf(m - M), e1 = __expf(m1 - M);
    float L = l*e0 + l1*e1;
    float* dst;
    if (isLig) dst = partL + ((size_t)((qt*16+q)*8 + h)*8 + slice)*18;
    else       dst = partP + ((size_t)((qt*16+q)*8 + h)*4 + slice)*18;
    dst[0] = M; dst[1] = L;
    dst[2]  = O0.x*e0 + b[2]*e1;  dst[3]  = O0.y*e0 + b[3]*e1;
    dst[4]  = O0.z*e0 + b[4]*e1;  dst[5]  = O0.w*e0 + b[5]*e1;
    dst[6]  = O1.x*e0 + b[6]*e1;  dst[7]  = O1.y*e0 + b[7]*e1;
    dst[8]  = O1.z*e0 + b[8]*e1;  dst[9]  = O1.w*e0 + b[9]*e1;
    dst[10] = O2.x*e0 + b[10]*e1; dst[11] = O2.y*e0 + b[11]*e1;
    dst[12] = O2.z*e0 + b[12]*e1; dst[13] = O2.w*e0 + b[13]*e1;
    dst[14] = O3.x*e0 + b[14]*e1; dst[15] = O3.y*e0 + b[15]*e1;
    dst[16] = O3.z*e0 + b[16]*e1; dst[17] = O3.w*e0 + b[17]*e1;
  }
}

// ---------------- merge partials + Wo proj + residual + LayerNorm ----------------
__global__ __launch_bounds__(128) void merge_ln(const float* __restrict__ partL, const float* __restrict__ partP,
                                                const float* __restrict__ lenh, const float* __restrict__ penh,
                                                const float* __restrict__ Wo, const float* __restrict__ bo,
                                                const float* __restrict__ g_l, const float* __restrict__ be_l,
                                                const float* __restrict__ g_p, const float* __restrict__ be_p,
                                                float* __restrict__ out){
  int r = blockIdx.x, t = threadIdx.x;
  int h = t >> 4, c = t & 15;
  int ns; const float* base;
  if (r < NL){ ns = 8; base = partL + ((size_t)(r*8 + h))*8*18; }
  else       { ns = 4; base = partP + ((size_t)((r-NL)*8 + h))*4*18; }
  float M = -1e30f;
  for (int s = 0; s < ns; s++) M = fmaxf(M, base[s*18]);
  float Lsum = 0.f, Osum = 0.f;
  for (int s = 0; s < ns; s++){
    float e = __expf(base[s*18] - M);
    Lsum = fmaf(e, base[s*18+1], Lsum);
    Osum = fmaf(e, base[s*18+2+c], Osum);
  }
  __shared__ float satt[HDIM];
  satt[t] = Osum / Lsum;
  __syncthreads();
  float o = bo[t];
  const float4* wr = (const float4*)(Wo + (size_t)t*HDIM);
  const float4* sv = (const float4*)satt;
  #pragma unroll 8
  for (int k = 0; k < 32; k++) o += dot4f(wr[k], sv[k]);
  const float* enh = (r < NL) ? (lenh + (size_t)r*HDIM) : (penh + (size_t)(r-NL)*HDIM);
  float x = enh[t] + o;
  __shared__ float red[HDIM];
  red[t] = x; __syncthreads();
  #pragma unroll
  for (int s = 64; s > 0; s >>= 1){ if (t < s) red[t] += red[t+s]; __syncthreads(); }
  float mu = red[0] * (1.f/128.f); __syncthreads();
  float dx = x - mu;
  red[t] = dx*dx; __syncthreads();
  #pragma unroll
  for (int s = 64; s > 0; s >>= 1){ if (t < s) red[t] += red[t+s]; __syncthreads(); }
  float var = red[0] * (1.f/128.f);
  float y = dx * rsqrtf(var + 1e-5f);
  if (r < NL){
    y = fmaf(y, g_l[t], be_l[t]);
    out[(size_t)r*HDIM + t] = y;
  } else {
    y = fmaf(y, g_p[t], be_p[t]);
    out[(size_t)NL*HDIM + (size_t)(r-NL)*HDIM + t] = y;
  }
}

extern "C" void kernel_launch(void* const* d_in, const int* in_sizes, int n_in,
                              void* d_out, int out_size, void* d_ws, size_t ws_size,
                              hipStream_t stream){
  const float* lf   = (const float*)d_in[0];
  const float* pf   = (const float*)d_in[1];
  const float* lc   = (const float*)d_in[2];
  const float* pc   = (const float*)d_in[3];
  const float* Wl   = (const float*)d_in[4];
  const float* bl   = (const float*)d_in[5];
  const float* Wp   = (const float*)d_in[6];
  const float* bp   = (const float*)d_in[7];
  const float* Wd1  = (const float*)d_in[8];
  const float* bd1  = (const float*)d_in[9];
  const float* Wd2  = (const float*)d_in[10];
  const float* bd2  = (const float*)d_in[11];
  const float* Wd3  = (const float*)d_in[12];
  const float* bd3  = (const float*)d_in[13];
  const float* Wgl  = (const float*)d_in[14];
  const float* bgl  = (const float*)d_in[15];
  const float* Wgp  = (const float*)d_in[16];
  const float* bgp  = (const float*)d_in[17];
  const float* Wqkv = (const float*)d_in[18];
  const float* bqkv = (const float*)d_in[19];
  const float* Wo   = (const float*)d_in[20];
  const float* bo   = (const float*)d_in[21];
  const float* g_l  = (const float*)d_in[22];
  const float* be_l = (const float*)d_in[23];
  const float* g_p  = (const float*)d_in[24];
  const float* be_p = (const float*)d_in[25];

  float* ws  = (float*)d_ws;
  float* out = (float*)d_out;
  float* wsw   = ws + WD3M_OFF;
  float* lig   = ws + LIG_OFF;
  float* poc   = ws + POC_OFF;
  float* lenh  = ws + LENH_OFF;
  float* penh  = ws + PENH_OFF;
  float* qkvl  = ws + QKVL_OFF;
  float* qkvp  = ws + QKVP_OFF;
  float* partL = ws + PARTL_OFF;
  float* partP = ws + PARTP_OFF;
  float* tab   = ws + TAB_OFF;   // aliases qkvl region; consumed before qkv_kernel writes

  prep_kernel<<<1, 128, 0, stream>>>(Wd3, bd3, wsw);
  table_kernel<<<TAB_N/256, 256, 0, stream>>>(Wd1, bd1, Wd2, bd2, wsw, tab);
  proj_kernel<<<384, 128, 0, stream>>>(lf, pf, Wl, bl, Wp, bp, lig, poc);
  agg_gate_fused<<<NL/4 + NP/4, 1024, 0, stream>>>(lc, pc, tab, lig, poc, Wgl, bgl, Wgp, bgp, lenh, penh);
  qkv_kernel<<<384, 384, 0, stream>>>(lenh, penh, Wqkv, bqkv, qkvl, qkvp);
  attn_part<<<512, 256, 0, stream>>>(qkvl, qkvp, partL, partP);
  merge_ln<<<1536, 128, 0, stream>>>(partL, partP, lenh, penh, Wo, bo, g_l, be_l, g_p, be_p, out);
}